// Round 4
// baseline (1125.988 us; speedup 1.0000x reference)
//
#include <hip/hip_runtime.h>
#include <math.h>

#define NPTS 500000
#define KH 129
#define NKEY 16384   // 32x32x16 cells of 8x8x16 voxels

__device__ __forceinline__ int rev4(int n) {
    return ((n & 3) << 6) | ((n & 12) << 2) | ((n & 48) >> 2) | ((n & 192) >> 6);
}

__device__ __forceinline__ void cmul(float ar, float ai, float br, float bi,
                                     float& cr, float& ci) {
    cr = ar * br - ai * bi;
    ci = ar * bi + ai * br;
}

// 16 independent 256-pt radix-4 DIT FFTs in LDS (SoA, line stride 257 floats).
__device__ void fft256x16(float* RE, float* IM, int tid, float sign) {
    const int line = tid >> 4, lane = tid & 15;
    float* re = RE + line * 257;
    float* im = IM + line * 257;
    __syncthreads();
    #pragma unroll
    for (int st = 0; st < 4; st++) {
        const int q = 1 << (2 * st);           // 1,4,16,64
        const float base = sign * 6.283185307179586f / (float)(q << 2);
        #pragma unroll
        for (int jj = 0; jj < 4; jj++) {
            const int j = lane + (jj << 4);    // 0..63
            const int pos = j & (q - 1);
            const int i0 = ((j >> (2 * st)) << (2 * st + 2)) + pos;
            const int i1 = i0 + q, i2 = i1 + q, i3 = i2 + q;
            float w1i, w1r;
            __sincosf(base * (float)pos, &w1i, &w1r);
            float w2r, w2i; cmul(w1r, w1i, w1r, w1i, w2r, w2i);
            float w3r, w3i; cmul(w2r, w2i, w1r, w1i, w3r, w3i);
            float ar = re[i0], ai = im[i0];
            float b0r = re[i1], b0i = im[i1];
            float c0r = re[i2], c0i = im[i2];
            float d0r = re[i3], d0i = im[i3];
            float br, bi; cmul(b0r, b0i, w1r, w1i, br, bi);
            float cr, ci; cmul(c0r, c0i, w2r, w2i, cr, ci);
            float dr, di; cmul(d0r, d0i, w3r, w3i, dr, di);
            float er = ar + cr, ei = ai + ci;
            float fr = ar - cr, fi = ai - ci;
            float gr = br + dr, gi = bi + di;
            float hr = br - dr, hi_ = bi - di;
            float sir = -sign * hi_, sii = sign * hr;   // sign*i*(b-d)
            re[i0] = er + gr;  im[i0] = ei + gi;
            re[i1] = fr + sir; im[i1] = fi + sii;
            re[i2] = er - gr;  im[i2] = ei - gi;
            re[i3] = fr - sir; im[i3] = fi - sii;
        }
        __syncthreads();
    }
}

__device__ __forceinline__ int cell_key(float x, float y, float z) {
    int ix = (int)(x * 256.0f), iy = (int)(y * 256.0f), iz = (int)(z * 256.0f);
    return ((ix >> 3) << 9) | ((iy >> 3) << 4) | (iz >> 4);
}

// ---- sort pass 1: histogram of cell keys ----
__global__ void k_hist(const float* __restrict__ V, int* __restrict__ cnt) {
    int i = blockIdx.x * blockDim.x + threadIdx.x;
    if (i >= NPTS) return;
    atomicAdd(&cnt[cell_key(V[3 * i], V[3 * i + 1], V[3 * i + 2])], 1);
}

// ---- sort pass 2: exclusive scan of 16384 counts (single block) ----
__global__ void k_scan(const int* __restrict__ cnt, int* __restrict__ off,
                       int* __restrict__ cnt2) {
    __shared__ int s[256];
    int t = threadIdx.x;
    int sum = 0;
    for (int j = 0; j < 64; j++) sum += cnt[t * 64 + j];
    s[t] = sum;
    __syncthreads();
    if (t == 0) { int run = 0; for (int j = 0; j < 256; j++) { int c = s[j]; s[j] = run; run += c; } }
    __syncthreads();
    int run = s[t];
    for (int j = 0; j < 64; j++) {
        int c = cnt[t * 64 + j];
        off[t * 64 + j] = run;
        cnt2[t * 64 + j] = run;
        run += c;
    }
    if (t == 255) off[NKEY] = run;   // == NPTS
}

// ---- sort pass 3 (packed): scatter coords+normals into cell order ----
__global__ void k_scatter_pk(const float* __restrict__ V, const float* __restrict__ N,
                             int* __restrict__ cnt2, float* __restrict__ Vs,
                             float* __restrict__ Nx, float* __restrict__ Ny,
                             float* __restrict__ Nz) {
    int i = blockIdx.x * blockDim.x + threadIdx.x;
    if (i >= NPTS) return;
    float x = V[3 * i], y = V[3 * i + 1], z = V[3 * i + 2];
    int s = atomicAdd(&cnt2[cell_key(x, y, z)], 1);
    Vs[3 * s] = x; Vs[3 * s + 1] = y; Vs[3 * s + 2] = z;
    Nx[s] = N[3 * i]; Ny[s] = N[3 * i + 1]; Nz[s] = N[3 * i + 2];
}

// ---- legacy sort pass 3: scatter indices (fallback path) ----
__global__ void k_scatter(const float* __restrict__ V, int* __restrict__ cnt2,
                          int* __restrict__ idx) {
    int i = blockIdx.x * blockDim.x + threadIdx.x;
    if (i >= NPTS) return;
    int s = atomicAdd(&cnt2[cell_key(V[3 * i], V[3 * i + 1], V[3 * i + 2])], 1);
    idx[s] = i;
}

// ---- fused 3-channel atomic-free rasterize. Block = 8x8x16 voxel tile ----
// grid (16,32,32): blockIdx.x=cz, y=cy, z=cx
__global__ void k_rastg3(const float* __restrict__ Vs, const float* __restrict__ Nx,
                         const float* __restrict__ Ny, const float* __restrict__ Nz,
                         const int* __restrict__ off,
                         float* __restrict__ R0, float* __restrict__ R1,
                         float* __restrict__ R2) {
    __shared__ float t0[1024], t1[1024], t2[1024];
    int t = threadIdx.x;
    #pragma unroll
    for (int q = 0; q < 4; q++) {
        t0[t + q * 256] = 0.0f; t1[t + q * 256] = 0.0f; t2[t + q * 256] = 0.0f;
    }
    __syncthreads();
    int CZ = blockIdx.x, CY = blockIdx.y, CX = blockIdx.z;
    int X0 = CX << 3, Y0 = CY << 3, Z0 = CZ << 4;
    #pragma unroll
    for (int cc = 0; cc < 8; cc++) {
        int cx = (CX - ((cc >> 2) & 1)) & 31;
        int cy = (CY - ((cc >> 1) & 1)) & 31;
        int cz = (CZ - (cc & 1)) & 15;
        int key = (cx << 9) | (cy << 4) | cz;
        int s = off[key], e = off[key + 1];
        for (int p = s + t; p < e; p += 256) {
            float xs = Vs[3 * p] * 256.0f, ys = Vs[3 * p + 1] * 256.0f, zs = Vs[3 * p + 2] * 256.0f;
            float vx = Nx[p], vy = Ny[p], vz = Nz[p];
            int ix0 = (int)xs, iy0 = (int)ys, iz0 = (int)zs;
            float fx = xs - ix0, fy = ys - iy0, fz = zs - iz0;
            #pragma unroll
            for (int c = 0; c < 8; c++) {
                int bx = (c >> 2) & 1, by = (c >> 1) & 1, bz = c & 1;
                int lx = ((bx ? ix0 + 1 : ix0) - X0) & 255;
                int ly = ((by ? iy0 + 1 : iy0) - Y0) & 255;
                int lz = ((bz ? iz0 + 1 : iz0) - Z0) & 255;
                if (lx < 8 && ly < 8 && lz < 16) {
                    float w = (bx ? fx : 1.0f - fx) * (by ? fy : 1.0f - fy) * (bz ? fz : 1.0f - fz);
                    int li = (((lx << 3) + ly) << 4) + lz;
                    atomicAdd(&t0[li], w * vx);
                    atomicAdd(&t1[li], w * vy);
                    atomicAdd(&t2[li], w * vz);
                }
            }
        }
    }
    __syncthreads();
    #pragma unroll
    for (int q = 0; q < 4; q++) {
        int l = t + q * 256;
        int lx = l >> 7, ly = (l >> 4) & 7, lz = l & 15;
        size_t a = (size_t)(((X0 + lx) << 16) | ((Y0 + ly) << 8) | (Z0 + lz));
        R0[a] = t0[l]; R1[a] = t1[l]; R2[a] = t2[l];
    }
}

// ---- per-channel packed rasterize (fallback B) ----
__global__ void k_rastgp(const float* __restrict__ Vs, const float* __restrict__ Nd,
                         const int* __restrict__ off, float* __restrict__ R) {
    __shared__ float tile[1024];
    int t = threadIdx.x;
    #pragma unroll
    for (int q = 0; q < 4; q++) tile[t + q * 256] = 0.0f;
    __syncthreads();
    int CZ = blockIdx.x, CY = blockIdx.y, CX = blockIdx.z;
    int X0 = CX << 3, Y0 = CY << 3, Z0 = CZ << 4;
    #pragma unroll
    for (int cc = 0; cc < 8; cc++) {
        int cx = (CX - ((cc >> 2) & 1)) & 31;
        int cy = (CY - ((cc >> 1) & 1)) & 31;
        int cz = (CZ - (cc & 1)) & 15;
        int key = (cx << 9) | (cy << 4) | cz;
        int s = off[key], e = off[key + 1];
        for (int p = s + t; p < e; p += 256) {
            float xs = Vs[3 * p] * 256.0f, ys = Vs[3 * p + 1] * 256.0f, zs = Vs[3 * p + 2] * 256.0f;
            float val = Nd[p];
            int ix0 = (int)xs, iy0 = (int)ys, iz0 = (int)zs;
            float fx = xs - ix0, fy = ys - iy0, fz = zs - iz0;
            #pragma unroll
            for (int c = 0; c < 8; c++) {
                int bx = (c >> 2) & 1, by = (c >> 1) & 1, bz = c & 1;
                int lx = ((bx ? ix0 + 1 : ix0) - X0) & 255;
                int ly = ((by ? iy0 + 1 : iy0) - Y0) & 255;
                int lz = ((bz ? iz0 + 1 : iz0) - Z0) & 255;
                if (lx < 8 && ly < 8 && lz < 16) {
                    float w = (bx ? fx : 1.0f - fx) * (by ? fy : 1.0f - fy) * (bz ? fz : 1.0f - fz);
                    atomicAdd(&tile[(((lx << 3) + ly) << 4) + lz], w * val);
                }
            }
        }
    }
    __syncthreads();
    #pragma unroll
    for (int q = 0; q < 4; q++) {
        int l = t + q * 256;
        int lx = l >> 7, ly = (l >> 4) & 7, lz = l & 15;
        R[(size_t)(((X0 + lx) << 16) | ((Y0 + ly) << 8) | (Z0 + lz))] = tile[l];
    }
}

// ---- legacy rasterize via idx (fallback C) ----
__global__ void k_rastg(const int* __restrict__ idx, const int* __restrict__ off,
                        const float* __restrict__ V, const float* __restrict__ N,
                        float* __restrict__ R, int d) {
    __shared__ float tile[1024];
    int t = threadIdx.x;
    #pragma unroll
    for (int q = 0; q < 4; q++) tile[t + q * 256] = 0.0f;
    __syncthreads();
    int CZ = blockIdx.x, CY = blockIdx.y, CX = blockIdx.z;
    int X0 = CX << 3, Y0 = CY << 3, Z0 = CZ << 4;
    #pragma unroll
    for (int cc = 0; cc < 8; cc++) {
        int cx = (CX - ((cc >> 2) & 1)) & 31;
        int cy = (CY - ((cc >> 1) & 1)) & 31;
        int cz = (CZ - (cc & 1)) & 15;
        int key = (cx << 9) | (cy << 4) | cz;
        int s = off[key], e = off[key + 1];
        for (int p = s + t; p < e; p += 256) {
            int i = idx[p];
            float xs = V[3 * i] * 256.0f, ys = V[3 * i + 1] * 256.0f, zs = V[3 * i + 2] * 256.0f;
            float val = N[3 * i + d];
            int ix0 = (int)xs, iy0 = (int)ys, iz0 = (int)zs;
            float fx = xs - ix0, fy = ys - iy0, fz = zs - iz0;
            #pragma unroll
            for (int c = 0; c < 8; c++) {
                int bx = (c >> 2) & 1, by = (c >> 1) & 1, bz = c & 1;
                int lx = ((bx ? ix0 + 1 : ix0) - X0) & 255;
                int ly = ((by ? iy0 + 1 : iy0) - Y0) & 255;
                int lz = ((bz ? iz0 + 1 : iz0) - Z0) & 255;
                if (lx < 8 && ly < 8 && lz < 16) {
                    float w = (bx ? fx : 1.0f - fx) * (by ? fy : 1.0f - fy) * (bz ? fz : 1.0f - fz);
                    atomicAdd(&tile[(((lx << 3) + ly) << 4) + lz], w * val);
                }
            }
        }
    }
    __syncthreads();
    #pragma unroll
    for (int q = 0; q < 4; q++) {
        int l = t + q * 256;
        int lx = l >> 7, ly = (l >> 4) & 7, lz = l & 15;
        R[(size_t)(((X0 + lx) << 16) | ((Y0 + ly) << 8) | (Z0 + lz))] = tile[l];
    }
}

// ---- forward rfft along z. Block: 16 (x,y)-lines. C layout [x][y][k], row khp ----
__global__ void k_rfft_z(const float* __restrict__ R, float2* __restrict__ C, int khp) {
    __shared__ float RE[16 * 257];
    __shared__ float IM[16 * 257];
    int x = blockIdx.x, y0 = blockIdx.y * 16, tid = threadIdx.x;
    #pragma unroll
    for (int l = 0; l < 16; l++) {
        float v = R[(((size_t)x << 8) + (y0 + l)) * 256 + tid];
        RE[l * 257 + rev4(tid)] = v;
        IM[l * 257 + rev4(tid)] = 0.0f;
    }
    fft256x16(RE, IM, tid, -1.0f);
    #pragma unroll
    for (int l = 0; l < 16; l++) {
        if (tid < KH) {
            C[(((size_t)x << 8) + (y0 + l)) * khp + tid] =
                make_float2(RE[l * 257 + tid], IM[l * 257 + tid]);
        }
    }
}

// ---- complex FFT along y, in place. Block: 16 k-columns at fixed x. ----
__global__ void k_fft_y(float2* __restrict__ C, int khp, float sign) {
    __shared__ float RE[16 * 257];
    __shared__ float IM[16 * 257];
    int x = blockIdx.x, k0 = blockIdx.y * 16, tid = threadIdx.x;
    int kl = tid & 15, k = k0 + kl;
    bool valid = (k < KH);
    float2* base = C + (size_t)x * 256 * khp + k;
    #pragma unroll
    for (int it = 0; it < 16; it++) {
        int y = (tid >> 4) + it * 16;
        float2 v = valid ? base[(size_t)y * khp] : make_float2(0.0f, 0.0f);
        RE[kl * 257 + rev4(y)] = v.x;
        IM[kl * 257 + rev4(y)] = v.y;
    }
    fft256x16(RE, IM, tid, sign);
    #pragma unroll
    for (int it = 0; it < 16; it++) {
        int y = (tid >> 4) + it * 16;
        if (valid) base[(size_t)y * khp] = make_float2(RE[kl * 257 + y], IM[kl * 257 + y]);
    }
}

// ---- forward FFT along x + spectral MAC into Acc; mode2 fuses inverse-x ----
__global__ void k_fft_x_acc(const float2* __restrict__ C, float2* __restrict__ Acc,
                            int khp, int mode, int d) {
    __shared__ float RE[16 * 257];
    __shared__ float IM[16 * 257];
    int y = blockIdx.x, k0 = blockIdx.y * 16, tid = threadIdx.x;
    int kl = tid & 15, k = k0 + kl;
    bool valid = (k < KH);
    size_t plane = (size_t)256 * khp;
    const float2* base = C + (size_t)y * khp + k;
    #pragma unroll
    for (int it = 0; it < 16; it++) {
        int n = (tid >> 4) + it * 16;
        float2 v = valid ? base[(size_t)n * plane] : make_float2(0.0f, 0.0f);
        RE[kl * 257 + rev4(n)] = v.x;
        IM[kl * 257 + rev4(n)] = v.y;
    }
    fft256x16(RE, IM, tid, -1.0f);
    float2* abase = Acc + (size_t)y * khp + k;
    float fy = (y < 128) ? (float)y : (float)(y - 256);
    float fz = (float)k;
    float vr[16], vi[16];
    #pragma unroll
    for (int it = 0; it < 16; it++) {
        int n = (tid >> 4) + it * 16;
        float fx = (n < 128) ? (float)n : (float)(n - 256);
        float f2 = fx * fx + fy * fy + fz * fz;
        float G = __expf(-0.0030517578125f * f2);          // exp(-0.5*(2*SIG*|f|/256)^2)
        float fd = (d == 0) ? fx : ((d == 1) ? fy : fz);
        float s = G * (6.283185307179586f * fd) / (1e-6f - 39.47841760435743f * f2);
        float xr = RE[kl * 257 + n], xi = IM[kl * 257 + n];
        float cr = s * xi, ci = -s * xr;                   // (-i*s)*v
        if (mode >= 1) {
            float2 old = valid ? abase[(size_t)n * plane] : make_float2(0.0f, 0.0f);
            cr += old.x; ci += old.y;
        }
        if (mode == 2) { vr[it] = cr; vi[it] = ci; }
        else if (valid) abase[(size_t)n * plane] = make_float2(cr, ci);
    }
    if (mode == 2) {
        __syncthreads();
        #pragma unroll
        for (int it = 0; it < 16; it++) {
            int n = (tid >> 4) + it * 16;
            RE[kl * 257 + rev4(n)] = vr[it];
            IM[kl * 257 + rev4(n)] = vi[it];
        }
        fft256x16(RE, IM, tid, 1.0f);
        #pragma unroll
        for (int it = 0; it < 16; it++) {
            int n = (tid >> 4) + it * 16;
            if (valid) abase[(size_t)n * plane] =
                make_float2(RE[kl * 257 + n], IM[kl * 257 + n]);
        }
    }
}

// ---- inverse rfft along z with Hermitian extension; 1/256^3 scale ----
__global__ void k_irfft_z(const float2* __restrict__ A, float* __restrict__ out, int khp) {
    __shared__ float RE[16 * 257];
    __shared__ float IM[16 * 257];
    int x = blockIdx.x, y0 = blockIdx.y * 16, tid = threadIdx.x;
    #pragma unroll
    for (int l = 0; l < 16; l++) {
        const float2* src = A + (((size_t)x << 8) + (y0 + l)) * khp;
        int n = tid;
        int k = (n <= 128) ? n : 256 - n;
        float2 v = src[k];
        RE[l * 257 + rev4(n)] = v.x;
        IM[l * 257 + rev4(n)] = (n <= 128) ? v.y : -v.y;
    }
    fft256x16(RE, IM, tid, 1.0f);
    const float sc = 1.0f / 16777216.0f;
    #pragma unroll
    for (int l = 0; l < 16; l++) {
        out[(((size_t)x << 8) + (y0 + l)) * 256 + tid] = RE[l * 257 + tid] * sc;
    }
}

// ---- cell-tiled interpolation: block per cell, phi halo tile in LDS ----
// grid (16,32,32): blockIdx.x=CZ, y=CY, z=CX. Tile 9x9x17 floats.
__global__ void k_interp_cell(const float* __restrict__ phi, const float* __restrict__ Vs,
                              const int* __restrict__ off, float* __restrict__ S) {
    __shared__ float tile[9 * 9 * 17];
    __shared__ float red[4];
    int t = threadIdx.x;
    int CZ = blockIdx.x, CY = blockIdx.y, CX = blockIdx.z;
    int X0 = CX << 3, Y0 = CY << 3, Z0 = CZ << 4;
    for (int j = t; j < 9 * 9 * 17; j += 256) {
        int lx = j / 153; int r = j - lx * 153; int ly = r / 17; int lz = r - ly * 17;
        int gx = (X0 + lx) & 255, gy = (Y0 + ly) & 255, gz = (Z0 + lz) & 255;
        tile[j] = phi[(size_t)((gx << 16) | (gy << 8) | gz)];
    }
    __syncthreads();
    int key = (CX << 9) | (CY << 4) | CZ;
    int s = off[key], e = off[key + 1];
    float acc = 0.0f;
    for (int p = s + t; p < e; p += 256) {
        float xs = Vs[3 * p] * 256.0f, ys = Vs[3 * p + 1] * 256.0f, zs = Vs[3 * p + 2] * 256.0f;
        int ix0 = (int)xs, iy0 = (int)ys, iz0 = (int)zs;
        float fx = xs - ix0, fy = ys - iy0, fz = zs - iz0;
        int lx = ix0 - X0, ly = iy0 - Y0, lz = iz0 - Z0;   // in [0,8)x[0,8)x[0,16)
        int b = lx * 153 + ly * 17 + lz;
        float c00 = tile[b]       * (1.0f - fz) + tile[b + 1]        * fz;
        float c01 = tile[b + 17]  * (1.0f - fz) + tile[b + 18]       * fz;
        float c10 = tile[b + 153] * (1.0f - fz) + tile[b + 154]      * fz;
        float c11 = tile[b + 170] * (1.0f - fz) + tile[b + 171]      * fz;
        float c0 = c00 * (1.0f - fy) + c01 * fy;
        float c1 = c10 * (1.0f - fy) + c11 * fy;
        acc += c0 * (1.0f - fx) + c1 * fx;
    }
    #pragma unroll
    for (int o = 32; o > 0; o >>= 1) acc += __shfl_down(acc, o, 64);
    if ((t & 63) == 0) red[t >> 6] = acc;
    __syncthreads();
    if (t == 0) atomicAdd(S, red[0] + red[1] + red[2] + red[3]);
}

// ---- legacy per-point interp (fallback) ----
__global__ void k_interp_sum(const float* __restrict__ phi, const float* __restrict__ V,
                             float* __restrict__ S) {
    int i = blockIdx.x * blockDim.x + threadIdx.x;
    float acc = 0.0f;
    if (i < NPTS) {
        float xs = V[3 * i + 0] * 256.0f;
        float ys = V[3 * i + 1] * 256.0f;
        float zs = V[3 * i + 2] * 256.0f;
        int ix0 = (int)floorf(xs), iy0 = (int)floorf(ys), iz0 = (int)floorf(zs);
        float fx = xs - (float)ix0, fy = ys - (float)iy0, fz = zs - (float)iz0;
        int ix1 = (ix0 + 1) & 255, iy1 = (iy0 + 1) & 255, iz1 = (iz0 + 1) & 255;
        #pragma unroll
        for (int c = 0; c < 8; c++) {
            int bx = (c >> 2) & 1, by = (c >> 1) & 1, bz = c & 1;
            int ix = bx ? ix1 : ix0, iy = by ? iy1 : iy0, iz = bz ? iz1 : iz0;
            float w = (bx ? fx : 1.0f - fx) * (by ? fy : 1.0f - fy) * (bz ? fz : 1.0f - fz);
            acc += w * phi[(((size_t)ix << 8) + (size_t)iy) * 256 + (size_t)iz];
        }
    }
    #pragma unroll
    for (int o = 32; o > 0; o >>= 1) acc += __shfl_down(acc, o, 64);
    if ((threadIdx.x & 63) == 0) atomicAdd(S, acc);
}

__global__ void k_scalars(const float* __restrict__ S, const float* __restrict__ phi,
                          float* __restrict__ sc_out) {
    float mean = S[0] * (1.0f / (float)NPTS);
    sc_out[0] = mean;
    sc_out[1] = 0.5f / fabsf(phi[0] - mean);
}

__global__ void k_scale(float* __restrict__ phi, const float* __restrict__ sc) {
    size_t i = (size_t)blockIdx.x * blockDim.x + threadIdx.x;
    float mean = sc[0], inv = sc[1];
    float4* p = (float4*)phi;
    float4 v = p[i];
    v.x = -(v.x - mean) * inv;
    v.y = -(v.y - mean) * inv;
    v.z = -(v.z - mean) * inv;
    v.w = -(v.w - mean) * inv;
    p[i] = v;
}

extern "C" void kernel_launch(void* const* d_in, const int* in_sizes, int n_in,
                              void* d_out, int out_size, void* d_ws, size_t ws_size,
                              hipStream_t stream) {
    const float* V = (const float*)d_in[0];
    const float* N = (const float*)d_in[1];
    float* out = (float*)d_out;

    const size_t RB   = 256ull * 256 * 256 * 4;               // 64 MiB
    const size_t C129 = 256ull * 256 * 129 * 8;
    const size_t C144 = 256ull * 256 * 144 * 8;
    const size_t SB_CNT = ((NKEY * 4 + 255) / 256) * 256;
    const size_t SB_OFF = (((NKEY + 1) * 4 + 255) / 256) * 256;
    const size_t SB_IDX = ((NPTS * 4 + 255) / 256) * 256;
    const size_t PK_VS  = ((NPTS * 3 * 4 + 255) / 256) * 256;
    const size_t PK_N   = ((NPTS * 4 + 255) / 256) * 256;
    const size_t SORT_CORE = SB_CNT * 2 + SB_OFF;             // cnt + cnt2 + off
    const size_t PACK = PK_VS + 3 * PK_N;

    // mode: 2=fused 3-channel packed, 1=per-channel packed, 0=legacy idx path
    int mode, khp; size_t cb;
    if      (ws_size >= 3 * RB + 2 * C144 + 256 + SORT_CORE + PACK) { mode = 2; khp = 144; cb = C144; }
    else if (ws_size >= 3 * RB + 2 * C129 + 256 + SORT_CORE + PACK) { mode = 2; khp = 129; cb = C129; }
    else if (ws_size >= RB + 2 * C144 + 256 + SORT_CORE + PACK)     { mode = 1; khp = 144; cb = C144; }
    else if (ws_size >= RB + 2 * C129 + 256 + SORT_CORE + PACK)     { mode = 1; khp = 129; cb = C129; }
    else if (ws_size >= RB + 2 * C144 + 256 + SORT_CORE + SB_IDX)   { mode = 0; khp = 144; cb = C144; }
    else if (ws_size >= RB + 2 * C129 + 256 + SORT_CORE + SB_IDX)   { mode = 0; khp = 129; cb = C129; }
    else return;

    char* ws = (char*)d_ws;
    int nR = (mode == 2) ? 3 : 1;
    float* R0 = (float*)ws;
    float* R1 = (float*)(ws + RB);
    float* R2 = (float*)(ws + 2 * RB);
    float2* C   = (float2*)(ws + nR * RB);
    float2* Acc = (float2*)(ws + nR * RB + cb);
    float*  sc  = (float*)(ws + nR * RB + 2 * cb);
    char* sb = ws + nR * RB + 2 * cb + 256;
    int* cnt  = (int*)sb;
    int* offp = (int*)(sb + SB_CNT);
    int* cnt2 = (int*)(sb + SB_CNT + SB_OFF);
    char* pb = sb + SORT_CORE;
    float* Vs = (float*)pb;
    float* Nxp = (float*)(pb + PK_VS);
    float* Nyp = (float*)(pb + PK_VS + PK_N);
    float* Nzp = (float*)(pb + PK_VS + 2 * PK_N);
    int* idx = (int*)pb;   // legacy path reuses pack region

    hipMemsetAsync(sc, 0, 16, stream);
    hipMemsetAsync(cnt, 0, NKEY * 4, stream);

    dim3 b256(256);
    dim3 g_z(256, 16);
    dim3 g_t(256, 9);
    dim3 g_pts((NPTS + 255) / 256);
    dim3 g_cell(16, 32, 32);   // cz, cy, cx

    k_hist<<<g_pts, b256, 0, stream>>>(V, cnt);
    k_scan<<<1, b256, 0, stream>>>(cnt, offp, cnt2);
    if (mode >= 1) k_scatter_pk<<<g_pts, b256, 0, stream>>>(V, N, cnt2, Vs, Nxp, Nyp, Nzp);
    else           k_scatter<<<g_pts, b256, 0, stream>>>(V, cnt2, idx);

    if (mode == 2) {
        k_rastg3<<<g_cell, b256, 0, stream>>>(Vs, Nxp, Nyp, Nzp, offp, R0, R1, R2);
        const float* Rd[3] = {R0, R1, R2};
        for (int d = 0; d < 3; d++) {
            k_rfft_z<<<g_z, b256, 0, stream>>>(Rd[d], C, khp);
            k_fft_y<<<g_t, b256, 0, stream>>>(C, khp, -1.0f);
            k_fft_x_acc<<<g_t, b256, 0, stream>>>(C, Acc, khp, d, d);
        }
    } else {
        const float* Np[3] = {Nxp, Nyp, Nzp};
        for (int d = 0; d < 3; d++) {
            if (mode == 1) k_rastgp<<<g_cell, b256, 0, stream>>>(Vs, Np[d], offp, R0);
            else           k_rastg<<<g_cell, b256, 0, stream>>>(idx, offp, V, N, R0, d);
            k_rfft_z<<<g_z, b256, 0, stream>>>(R0, C, khp);
            k_fft_y<<<g_t, b256, 0, stream>>>(C, khp, -1.0f);
            k_fft_x_acc<<<g_t, b256, 0, stream>>>(C, Acc, khp, d, d);
        }
    }

    k_fft_y<<<g_t, b256, 0, stream>>>(Acc, khp, 1.0f);    // inverse y
    k_irfft_z<<<g_z, b256, 0, stream>>>(Acc, out, khp);   // inverse z + scale

    if (mode >= 1) k_interp_cell<<<g_cell, b256, 0, stream>>>(out, Vs, offp, sc);
    else           k_interp_sum<<<g_pts, b256, 0, stream>>>(out, V, sc);
    k_scalars<<<1, 1, 0, stream>>>(sc, out, sc + 1);
    k_scale<<<16777216 / 4 / 256, 256, 0, stream>>>(out, sc + 1);
}

// Round 5
// 1015.409 us; speedup vs baseline: 1.1089x; 1.1089x over previous
//
#include <hip/hip_runtime.h>
#include <math.h>

#define NPTS 500000
#define KH 129
#define NKEY 16384   // 32x32x16 cells of 8x8x16 voxels

__device__ __forceinline__ int rev4(int n) {
    return ((n & 3) << 6) | ((n & 12) << 2) | ((n & 48) >> 2) | ((n & 192) >> 6);
}

__device__ __forceinline__ void cmul(float ar, float ai, float br, float bi,
                                     float& cr, float& ci) {
    cr = ar * br - ai * bi;
    ci = ar * bi + ai * br;
}

// 16 independent 256-pt radix-4 DIT FFTs in LDS (SoA, line stride 257 floats).
__device__ void fft256x16(float* RE, float* IM, int tid, float sign) {
    const int line = tid >> 4, lane = tid & 15;
    float* re = RE + line * 257;
    float* im = IM + line * 257;
    __syncthreads();
    #pragma unroll
    for (int st = 0; st < 4; st++) {
        const int q = 1 << (2 * st);           // 1,4,16,64
        const float base = sign * 6.283185307179586f / (float)(q << 2);
        #pragma unroll
        for (int jj = 0; jj < 4; jj++) {
            const int j = lane + (jj << 4);    // 0..63
            const int pos = j & (q - 1);
            const int i0 = ((j >> (2 * st)) << (2 * st + 2)) + pos;
            const int i1 = i0 + q, i2 = i1 + q, i3 = i2 + q;
            float w1i, w1r;
            __sincosf(base * (float)pos, &w1i, &w1r);
            float w2r, w2i; cmul(w1r, w1i, w1r, w1i, w2r, w2i);
            float w3r, w3i; cmul(w2r, w2i, w1r, w1i, w3r, w3i);
            float ar = re[i0], ai = im[i0];
            float b0r = re[i1], b0i = im[i1];
            float c0r = re[i2], c0i = im[i2];
            float d0r = re[i3], d0i = im[i3];
            float br, bi; cmul(b0r, b0i, w1r, w1i, br, bi);
            float cr, ci; cmul(c0r, c0i, w2r, w2i, cr, ci);
            float dr, di; cmul(d0r, d0i, w3r, w3i, dr, di);
            float er = ar + cr, ei = ai + ci;
            float fr = ar - cr, fi = ai - ci;
            float gr = br + dr, gi = bi + di;
            float hr = br - dr, hi_ = bi - di;
            float sir = -sign * hi_, sii = sign * hr;   // sign*i*(b-d)
            re[i0] = er + gr;  im[i0] = ei + gi;
            re[i1] = fr + sir; im[i1] = fi + sii;
            re[i2] = er - gr;  im[i2] = ei - gi;
            re[i3] = fr - sir; im[i3] = fi - sii;
        }
        __syncthreads();
    }
}

__device__ __forceinline__ int cell_key(float x, float y, float z) {
    int ix = (int)(x * 256.0f), iy = (int)(y * 256.0f), iz = (int)(z * 256.0f);
    return ((ix >> 3) << 9) | ((iy >> 3) << 4) | (iz >> 4);
}

// ---- sort pass 1: histogram of cell keys ----
__global__ void k_hist(const float* __restrict__ V, int* __restrict__ cnt) {
    int i = blockIdx.x * blockDim.x + threadIdx.x;
    if (i >= NPTS) return;
    atomicAdd(&cnt[cell_key(V[3 * i], V[3 * i + 1], V[3 * i + 2])], 1);
}

// ---- sort pass 2: exclusive scan of 16384 counts (single block) ----
__global__ void k_scan(const int* __restrict__ cnt, int* __restrict__ off,
                       int* __restrict__ cnt2) {
    __shared__ int s[256];
    int t = threadIdx.x;
    int sum = 0;
    for (int j = 0; j < 64; j++) sum += cnt[t * 64 + j];
    s[t] = sum;
    __syncthreads();
    if (t == 0) { int run = 0; for (int j = 0; j < 256; j++) { int c = s[j]; s[j] = run; run += c; } }
    __syncthreads();
    int run = s[t];
    for (int j = 0; j < 64; j++) {
        int c = cnt[t * 64 + j];
        off[t * 64 + j] = run;
        cnt2[t * 64 + j] = run;
        run += c;
    }
    if (t == 255) off[NKEY] = run;   // == NPTS
}

// ---- sort pass 3 (packed): scatter coords+normals into cell order ----
__global__ void k_scatter_pk(const float* __restrict__ V, const float* __restrict__ N,
                             int* __restrict__ cnt2, float* __restrict__ Vs,
                             float* __restrict__ Nx, float* __restrict__ Ny,
                             float* __restrict__ Nz) {
    int i = blockIdx.x * blockDim.x + threadIdx.x;
    if (i >= NPTS) return;
    float x = V[3 * i], y = V[3 * i + 1], z = V[3 * i + 2];
    int s = atomicAdd(&cnt2[cell_key(x, y, z)], 1);
    Vs[3 * s] = x; Vs[3 * s + 1] = y; Vs[3 * s + 2] = z;
    Nx[s] = N[3 * i]; Ny[s] = N[3 * i + 1]; Nz[s] = N[3 * i + 2];
}

// ---- legacy sort pass 3: scatter indices (fallback path) ----
__global__ void k_scatter(const float* __restrict__ V, int* __restrict__ cnt2,
                          int* __restrict__ idx) {
    int i = blockIdx.x * blockDim.x + threadIdx.x;
    if (i >= NPTS) return;
    int s = atomicAdd(&cnt2[cell_key(V[3 * i], V[3 * i + 1], V[3 * i + 2])], 1);
    idx[s] = i;
}

// ---- fused 3-channel atomic-free rasterize. Block = 8x8x16 voxel tile ----
// grid (16,32,32): blockIdx.x=cz, y=cy, z=cx
__global__ void k_rastg3(const float* __restrict__ Vs, const float* __restrict__ Nx,
                         const float* __restrict__ Ny, const float* __restrict__ Nz,
                         const int* __restrict__ off,
                         float* __restrict__ R0, float* __restrict__ R1,
                         float* __restrict__ R2) {
    __shared__ float t0[1024], t1[1024], t2[1024];
    int t = threadIdx.x;
    #pragma unroll
    for (int q = 0; q < 4; q++) {
        t0[t + q * 256] = 0.0f; t1[t + q * 256] = 0.0f; t2[t + q * 256] = 0.0f;
    }
    __syncthreads();
    int CZ = blockIdx.x, CY = blockIdx.y, CX = blockIdx.z;
    int X0 = CX << 3, Y0 = CY << 3, Z0 = CZ << 4;
    #pragma unroll
    for (int cc = 0; cc < 8; cc++) {
        int cx = (CX - ((cc >> 2) & 1)) & 31;
        int cy = (CY - ((cc >> 1) & 1)) & 31;
        int cz = (CZ - (cc & 1)) & 15;
        int key = (cx << 9) | (cy << 4) | cz;
        int s = off[key], e = off[key + 1];
        for (int p = s + t; p < e; p += 256) {
            float xs = Vs[3 * p] * 256.0f, ys = Vs[3 * p + 1] * 256.0f, zs = Vs[3 * p + 2] * 256.0f;
            float vx = Nx[p], vy = Ny[p], vz = Nz[p];
            int ix0 = (int)xs, iy0 = (int)ys, iz0 = (int)zs;
            float fx = xs - ix0, fy = ys - iy0, fz = zs - iz0;
            #pragma unroll
            for (int c = 0; c < 8; c++) {
                int bx = (c >> 2) & 1, by = (c >> 1) & 1, bz = c & 1;
                int lx = ((bx ? ix0 + 1 : ix0) - X0) & 255;
                int ly = ((by ? iy0 + 1 : iy0) - Y0) & 255;
                int lz = ((bz ? iz0 + 1 : iz0) - Z0) & 255;
                if (lx < 8 && ly < 8 && lz < 16) {
                    float w = (bx ? fx : 1.0f - fx) * (by ? fy : 1.0f - fy) * (bz ? fz : 1.0f - fz);
                    int li = (((lx << 3) + ly) << 4) + lz;
                    atomicAdd(&t0[li], w * vx);
                    atomicAdd(&t1[li], w * vy);
                    atomicAdd(&t2[li], w * vz);
                }
            }
        }
    }
    __syncthreads();
    #pragma unroll
    for (int q = 0; q < 4; q++) {
        int l = t + q * 256;
        int lx = l >> 7, ly = (l >> 4) & 7, lz = l & 15;
        size_t a = (size_t)(((X0 + lx) << 16) | ((Y0 + ly) << 8) | (Z0 + lz));
        R0[a] = t0[l]; R1[a] = t1[l]; R2[a] = t2[l];
    }
}

// ---- weight rasterize: same but val = 1 (builds W = sum of trilinear weights) ----
__global__ void k_rastg1(const float* __restrict__ Vs, const int* __restrict__ off,
                         float* __restrict__ R) {
    __shared__ float tile[1024];
    int t = threadIdx.x;
    #pragma unroll
    for (int q = 0; q < 4; q++) tile[t + q * 256] = 0.0f;
    __syncthreads();
    int CZ = blockIdx.x, CY = blockIdx.y, CX = blockIdx.z;
    int X0 = CX << 3, Y0 = CY << 3, Z0 = CZ << 4;
    #pragma unroll
    for (int cc = 0; cc < 8; cc++) {
        int cx = (CX - ((cc >> 2) & 1)) & 31;
        int cy = (CY - ((cc >> 1) & 1)) & 31;
        int cz = (CZ - (cc & 1)) & 15;
        int key = (cx << 9) | (cy << 4) | cz;
        int s = off[key], e = off[key + 1];
        for (int p = s + t; p < e; p += 256) {
            float xs = Vs[3 * p] * 256.0f, ys = Vs[3 * p + 1] * 256.0f, zs = Vs[3 * p + 2] * 256.0f;
            int ix0 = (int)xs, iy0 = (int)ys, iz0 = (int)zs;
            float fx = xs - ix0, fy = ys - iy0, fz = zs - iz0;
            #pragma unroll
            for (int c = 0; c < 8; c++) {
                int bx = (c >> 2) & 1, by = (c >> 1) & 1, bz = c & 1;
                int lx = ((bx ? ix0 + 1 : ix0) - X0) & 255;
                int ly = ((by ? iy0 + 1 : iy0) - Y0) & 255;
                int lz = ((bz ? iz0 + 1 : iz0) - Z0) & 255;
                if (lx < 8 && ly < 8 && lz < 16) {
                    float w = (bx ? fx : 1.0f - fx) * (by ? fy : 1.0f - fy) * (bz ? fz : 1.0f - fz);
                    atomicAdd(&tile[(((lx << 3) + ly) << 4) + lz], w);
                }
            }
        }
    }
    __syncthreads();
    #pragma unroll
    for (int q = 0; q < 4; q++) {
        int l = t + q * 256;
        int lx = l >> 7, ly = (l >> 4) & 7, lz = l & 15;
        R[(size_t)(((X0 + lx) << 16) | ((Y0 + ly) << 8) | (Z0 + lz))] = tile[l];
    }
}

// ---- per-channel packed rasterize (fallback B) ----
__global__ void k_rastgp(const float* __restrict__ Vs, const float* __restrict__ Nd,
                         const int* __restrict__ off, float* __restrict__ R) {
    __shared__ float tile[1024];
    int t = threadIdx.x;
    #pragma unroll
    for (int q = 0; q < 4; q++) tile[t + q * 256] = 0.0f;
    __syncthreads();
    int CZ = blockIdx.x, CY = blockIdx.y, CX = blockIdx.z;
    int X0 = CX << 3, Y0 = CY << 3, Z0 = CZ << 4;
    #pragma unroll
    for (int cc = 0; cc < 8; cc++) {
        int cx = (CX - ((cc >> 2) & 1)) & 31;
        int cy = (CY - ((cc >> 1) & 1)) & 31;
        int cz = (CZ - (cc & 1)) & 15;
        int key = (cx << 9) | (cy << 4) | cz;
        int s = off[key], e = off[key + 1];
        for (int p = s + t; p < e; p += 256) {
            float xs = Vs[3 * p] * 256.0f, ys = Vs[3 * p + 1] * 256.0f, zs = Vs[3 * p + 2] * 256.0f;
            float val = Nd[p];
            int ix0 = (int)xs, iy0 = (int)ys, iz0 = (int)zs;
            float fx = xs - ix0, fy = ys - iy0, fz = zs - iz0;
            #pragma unroll
            for (int c = 0; c < 8; c++) {
                int bx = (c >> 2) & 1, by = (c >> 1) & 1, bz = c & 1;
                int lx = ((bx ? ix0 + 1 : ix0) - X0) & 255;
                int ly = ((by ? iy0 + 1 : iy0) - Y0) & 255;
                int lz = ((bz ? iz0 + 1 : iz0) - Z0) & 255;
                if (lx < 8 && ly < 8 && lz < 16) {
                    float w = (bx ? fx : 1.0f - fx) * (by ? fy : 1.0f - fy) * (bz ? fz : 1.0f - fz);
                    atomicAdd(&tile[(((lx << 3) + ly) << 4) + lz], w * val);
                }
            }
        }
    }
    __syncthreads();
    #pragma unroll
    for (int q = 0; q < 4; q++) {
        int l = t + q * 256;
        int lx = l >> 7, ly = (l >> 4) & 7, lz = l & 15;
        R[(size_t)(((X0 + lx) << 16) | ((Y0 + ly) << 8) | (Z0 + lz))] = tile[l];
    }
}

// ---- legacy rasterize via idx (fallback C) ----
__global__ void k_rastg(const int* __restrict__ idx, const int* __restrict__ off,
                        const float* __restrict__ V, const float* __restrict__ N,
                        float* __restrict__ R, int d) {
    __shared__ float tile[1024];
    int t = threadIdx.x;
    #pragma unroll
    for (int q = 0; q < 4; q++) tile[t + q * 256] = 0.0f;
    __syncthreads();
    int CZ = blockIdx.x, CY = blockIdx.y, CX = blockIdx.z;
    int X0 = CX << 3, Y0 = CY << 3, Z0 = CZ << 4;
    #pragma unroll
    for (int cc = 0; cc < 8; cc++) {
        int cx = (CX - ((cc >> 2) & 1)) & 31;
        int cy = (CY - ((cc >> 1) & 1)) & 31;
        int cz = (CZ - (cc & 1)) & 15;
        int key = (cx << 9) | (cy << 4) | cz;
        int s = off[key], e = off[key + 1];
        for (int p = s + t; p < e; p += 256) {
            int i = idx[p];
            float xs = V[3 * i] * 256.0f, ys = V[3 * i + 1] * 256.0f, zs = V[3 * i + 2] * 256.0f;
            float val = N[3 * i + d];
            int ix0 = (int)xs, iy0 = (int)ys, iz0 = (int)zs;
            float fx = xs - ix0, fy = ys - iy0, fz = zs - iz0;
            #pragma unroll
            for (int c = 0; c < 8; c++) {
                int bx = (c >> 2) & 1, by = (c >> 1) & 1, bz = c & 1;
                int lx = ((bx ? ix0 + 1 : ix0) - X0) & 255;
                int ly = ((by ? iy0 + 1 : iy0) - Y0) & 255;
                int lz = ((bz ? iz0 + 1 : iz0) - Z0) & 255;
                if (lx < 8 && ly < 8 && lz < 16) {
                    float w = (bx ? fx : 1.0f - fx) * (by ? fy : 1.0f - fy) * (bz ? fz : 1.0f - fz);
                    atomicAdd(&tile[(((lx << 3) + ly) << 4) + lz], w * val);
                }
            }
        }
    }
    __syncthreads();
    #pragma unroll
    for (int q = 0; q < 4; q++) {
        int l = t + q * 256;
        int lx = l >> 7, ly = (l >> 4) & 7, lz = l & 15;
        R[(size_t)(((X0 + lx) << 16) | ((Y0 + ly) << 8) | (Z0 + lz))] = tile[l];
    }
}

// ---- forward rfft along z. Block: 16 (x,y)-lines. C layout [x][y][k], row khp ----
__global__ void k_rfft_z(const float* __restrict__ R, float2* __restrict__ C, int khp) {
    __shared__ float RE[16 * 257];
    __shared__ float IM[16 * 257];
    int x = blockIdx.x, y0 = blockIdx.y * 16, tid = threadIdx.x;
    #pragma unroll
    for (int l = 0; l < 16; l++) {
        float v = R[(((size_t)x << 8) + (y0 + l)) * 256 + tid];
        RE[l * 257 + rev4(tid)] = v;
        IM[l * 257 + rev4(tid)] = 0.0f;
    }
    fft256x16(RE, IM, tid, -1.0f);
    #pragma unroll
    for (int l = 0; l < 16; l++) {
        if (tid < KH) {
            C[(((size_t)x << 8) + (y0 + l)) * khp + tid] =
                make_float2(RE[l * 257 + tid], IM[l * 257 + tid]);
        }
    }
}

// ---- complex FFT along y, in place. Block: 16 k-columns at fixed x. ----
__global__ void k_fft_y(float2* __restrict__ C, int khp, float sign) {
    __shared__ float RE[16 * 257];
    __shared__ float IM[16 * 257];
    int x = blockIdx.x, k0 = blockIdx.y * 16, tid = threadIdx.x;
    int kl = tid & 15, k = k0 + kl;
    bool valid = (k < KH);
    float2* base = C + (size_t)x * 256 * khp + k;
    #pragma unroll
    for (int it = 0; it < 16; it++) {
        int y = (tid >> 4) + it * 16;
        float2 v = valid ? base[(size_t)y * khp] : make_float2(0.0f, 0.0f);
        RE[kl * 257 + rev4(y)] = v.x;
        IM[kl * 257 + rev4(y)] = v.y;
    }
    fft256x16(RE, IM, tid, sign);
    #pragma unroll
    for (int it = 0; it < 16; it++) {
        int y = (tid >> 4) + it * 16;
        if (valid) base[(size_t)y * khp] = make_float2(RE[kl * 257 + y], IM[kl * 257 + y]);
    }
}

// ---- forward FFT along x + spectral MAC into Acc; mode2 fuses inverse-x ----
__global__ void k_fft_x_acc(const float2* __restrict__ C, float2* __restrict__ Acc,
                            int khp, int mode, int d) {
    __shared__ float RE[16 * 257];
    __shared__ float IM[16 * 257];
    int y = blockIdx.x, k0 = blockIdx.y * 16, tid = threadIdx.x;
    int kl = tid & 15, k = k0 + kl;
    bool valid = (k < KH);
    size_t plane = (size_t)256 * khp;
    const float2* base = C + (size_t)y * khp + k;
    #pragma unroll
    for (int it = 0; it < 16; it++) {
        int n = (tid >> 4) + it * 16;
        float2 v = valid ? base[(size_t)n * plane] : make_float2(0.0f, 0.0f);
        RE[kl * 257 + rev4(n)] = v.x;
        IM[kl * 257 + rev4(n)] = v.y;
    }
    fft256x16(RE, IM, tid, -1.0f);
    float2* abase = Acc + (size_t)y * khp + k;
    float fy = (y < 128) ? (float)y : (float)(y - 256);
    float fz = (float)k;
    float vr[16], vi[16];
    #pragma unroll
    for (int it = 0; it < 16; it++) {
        int n = (tid >> 4) + it * 16;
        float fx = (n < 128) ? (float)n : (float)(n - 256);
        float f2 = fx * fx + fy * fy + fz * fz;
        float G = __expf(-0.0030517578125f * f2);          // exp(-0.5*(2*SIG*|f|/256)^2)
        float fd = (d == 0) ? fx : ((d == 1) ? fy : fz);
        float s = G * (6.283185307179586f * fd) / (1e-6f - 39.47841760435743f * f2);
        float xr = RE[kl * 257 + n], xi = IM[kl * 257 + n];
        float cr = s * xi, ci = -s * xr;                   // (-i*s)*v
        if (mode >= 1) {
            float2 old = valid ? abase[(size_t)n * plane] : make_float2(0.0f, 0.0f);
            cr += old.x; ci += old.y;
        }
        if (mode == 2) { vr[it] = cr; vi[it] = ci; }
        else if (valid) abase[(size_t)n * plane] = make_float2(cr, ci);
    }
    if (mode == 2) {
        __syncthreads();
        #pragma unroll
        for (int it = 0; it < 16; it++) {
            int n = (tid >> 4) + it * 16;
            RE[kl * 257 + rev4(n)] = vr[it];
            IM[kl * 257 + rev4(n)] = vi[it];
        }
        fft256x16(RE, IM, tid, 1.0f);
        #pragma unroll
        for (int it = 0; it < 16; it++) {
            int n = (tid >> 4) + it * 16;
            if (valid) abase[(size_t)n * plane] =
                make_float2(RE[kl * 257 + n], IM[kl * 257 + n]);
        }
    }
}

// ---- inverse rfft along z; optional fused dot(W, phi) for the mean ----
__global__ void k_irfft_z(const float2* __restrict__ A, float* __restrict__ out, int khp,
                          const float* __restrict__ W, float* __restrict__ S, int fuse) {
    __shared__ float RE[16 * 257];
    __shared__ float IM[16 * 257];
    __shared__ float red[4];
    int x = blockIdx.x, y0 = blockIdx.y * 16, tid = threadIdx.x;
    #pragma unroll
    for (int l = 0; l < 16; l++) {
        const float2* src = A + (((size_t)x << 8) + (y0 + l)) * khp;
        int n = tid;
        int k = (n <= 128) ? n : 256 - n;
        float2 v = src[k];
        RE[l * 257 + rev4(n)] = v.x;
        IM[l * 257 + rev4(n)] = (n <= 128) ? v.y : -v.y;
    }
    fft256x16(RE, IM, tid, 1.0f);
    const float sc = 1.0f / 16777216.0f;
    float acc = 0.0f;
    #pragma unroll
    for (int l = 0; l < 16; l++) {
        size_t a = (((size_t)x << 8) + (y0 + l)) * 256 + tid;
        float v = RE[l * 257 + tid] * sc;
        out[a] = v;
        if (fuse) acc += v * W[a];
    }
    if (fuse) {
        #pragma unroll
        for (int o = 32; o > 0; o >>= 1) acc += __shfl_down(acc, o, 64);
        if ((tid & 63) == 0) red[tid >> 6] = acc;
        __syncthreads();
        if (tid == 0) atomicAdd(S, red[0] + red[1] + red[2] + red[3]);
    }
}

// ---- legacy per-point interp (fallback) ----
__global__ void k_interp_sum(const float* __restrict__ phi, const float* __restrict__ V,
                             float* __restrict__ S) {
    int i = blockIdx.x * blockDim.x + threadIdx.x;
    float acc = 0.0f;
    if (i < NPTS) {
        float xs = V[3 * i + 0] * 256.0f;
        float ys = V[3 * i + 1] * 256.0f;
        float zs = V[3 * i + 2] * 256.0f;
        int ix0 = (int)floorf(xs), iy0 = (int)floorf(ys), iz0 = (int)floorf(zs);
        float fx = xs - (float)ix0, fy = ys - (float)iy0, fz = zs - (float)iz0;
        int ix1 = (ix0 + 1) & 255, iy1 = (iy0 + 1) & 255, iz1 = (iz0 + 1) & 255;
        #pragma unroll
        for (int c = 0; c < 8; c++) {
            int bx = (c >> 2) & 1, by = (c >> 1) & 1, bz = c & 1;
            int ix = bx ? ix1 : ix0, iy = by ? iy1 : iy0, iz = bz ? iz1 : iz0;
            float w = (bx ? fx : 1.0f - fx) * (by ? fy : 1.0f - fy) * (bz ? fz : 1.0f - fz);
            acc += w * phi[(((size_t)ix << 8) + (size_t)iy) * 256 + (size_t)iz];
        }
    }
    #pragma unroll
    for (int o = 32; o > 0; o >>= 1) acc += __shfl_down(acc, o, 64);
    if ((threadIdx.x & 63) == 0) atomicAdd(S, acc);
}

__global__ void k_scalars(const float* __restrict__ S, const float* __restrict__ phi,
                          float* __restrict__ sc_out) {
    float mean = S[0] * (1.0f / (float)NPTS);
    sc_out[0] = mean;
    sc_out[1] = 0.5f / fabsf(phi[0] - mean);
}

__global__ void k_scale(float* __restrict__ phi, const float* __restrict__ sc) {
    size_t i = (size_t)blockIdx.x * blockDim.x + threadIdx.x;
    float mean = sc[0], inv = sc[1];
    float4* p = (float4*)phi;
    float4 v = p[i];
    v.x = -(v.x - mean) * inv;
    v.y = -(v.y - mean) * inv;
    v.z = -(v.z - mean) * inv;
    v.w = -(v.w - mean) * inv;
    p[i] = v;
}

extern "C" void kernel_launch(void* const* d_in, const int* in_sizes, int n_in,
                              void* d_out, int out_size, void* d_ws, size_t ws_size,
                              hipStream_t stream) {
    const float* V = (const float*)d_in[0];
    const float* N = (const float*)d_in[1];
    float* out = (float*)d_out;

    const size_t RB   = 256ull * 256 * 256 * 4;               // 64 MiB
    const size_t C129 = 256ull * 256 * 129 * 8;
    const size_t C144 = 256ull * 256 * 144 * 8;
    const size_t SB_CNT = ((NKEY * 4 + 255) / 256) * 256;
    const size_t SB_OFF = (((NKEY + 1) * 4 + 255) / 256) * 256;
    const size_t SB_IDX = ((NPTS * 4 + 255) / 256) * 256;
    const size_t PK_VS  = ((NPTS * 3 * 4 + 255) / 256) * 256;
    const size_t PK_N   = ((NPTS * 4 + 255) / 256) * 256;
    const size_t SORT_CORE = SB_CNT * 2 + SB_OFF;             // cnt + cnt2 + off
    const size_t PACK = PK_VS + 3 * PK_N;

    // mode: 2=fused 3-channel packed (+W-dot fusion), 1=per-channel packed, 0=legacy
    int mode, khp; size_t cb;
    if      (ws_size >= 3 * RB + 2 * C144 + 256 + SORT_CORE + PACK) { mode = 2; khp = 144; cb = C144; }
    else if (ws_size >= 3 * RB + 2 * C129 + 256 + SORT_CORE + PACK) { mode = 2; khp = 129; cb = C129; }
    else if (ws_size >= RB + 2 * C144 + 256 + SORT_CORE + PACK)     { mode = 1; khp = 144; cb = C144; }
    else if (ws_size >= RB + 2 * C129 + 256 + SORT_CORE + PACK)     { mode = 1; khp = 129; cb = C129; }
    else if (ws_size >= RB + 2 * C144 + 256 + SORT_CORE + SB_IDX)   { mode = 0; khp = 144; cb = C144; }
    else if (ws_size >= RB + 2 * C129 + 256 + SORT_CORE + SB_IDX)   { mode = 0; khp = 129; cb = C129; }
    else return;

    char* ws = (char*)d_ws;
    int nR = (mode == 2) ? 3 : 1;
    float* R0 = (float*)ws;
    float* R1 = (float*)(ws + RB);
    float* R2 = (float*)(ws + 2 * RB);
    float2* C   = (float2*)(ws + nR * RB);
    float2* Acc = (float2*)(ws + nR * RB + cb);
    float*  sc  = (float*)(ws + nR * RB + 2 * cb);
    char* sb = ws + nR * RB + 2 * cb + 256;
    int* cnt  = (int*)sb;
    int* offp = (int*)(sb + SB_CNT);
    int* cnt2 = (int*)(sb + SB_CNT + SB_OFF);
    char* pb = sb + SORT_CORE;
    float* Vs = (float*)pb;
    float* Nxp = (float*)(pb + PK_VS);
    float* Nyp = (float*)(pb + PK_VS + PK_N);
    float* Nzp = (float*)(pb + PK_VS + 2 * PK_N);
    int* idx = (int*)pb;   // legacy path reuses pack region

    hipMemsetAsync(sc, 0, 16, stream);
    hipMemsetAsync(cnt, 0, NKEY * 4, stream);

    dim3 b256(256);
    dim3 g_z(256, 16);
    dim3 g_t(256, 9);
    dim3 g_pts((NPTS + 255) / 256);
    dim3 g_cell(16, 32, 32);   // cz, cy, cx

    k_hist<<<g_pts, b256, 0, stream>>>(V, cnt);
    k_scan<<<1, b256, 0, stream>>>(cnt, offp, cnt2);
    if (mode >= 1) k_scatter_pk<<<g_pts, b256, 0, stream>>>(V, N, cnt2, Vs, Nxp, Nyp, Nzp);
    else           k_scatter<<<g_pts, b256, 0, stream>>>(V, cnt2, idx);

    if (mode == 2) {
        k_rastg3<<<g_cell, b256, 0, stream>>>(Vs, Nxp, Nyp, Nzp, offp, R0, R1, R2);
        // d = 0 consumes R0, then R0 is recycled to hold the weight grid W
        k_rfft_z<<<g_z, b256, 0, stream>>>(R0, C, khp);
        k_fft_y<<<g_t, b256, 0, stream>>>(C, khp, -1.0f);
        k_fft_x_acc<<<g_t, b256, 0, stream>>>(C, Acc, khp, 0, 0);
        k_rastg1<<<g_cell, b256, 0, stream>>>(Vs, offp, R0);          // W into R0
        // d = 1
        k_rfft_z<<<g_z, b256, 0, stream>>>(R1, C, khp);
        k_fft_y<<<g_t, b256, 0, stream>>>(C, khp, -1.0f);
        k_fft_x_acc<<<g_t, b256, 0, stream>>>(C, Acc, khp, 1, 1);
        // d = 2 (fuses inverse-x)
        k_rfft_z<<<g_z, b256, 0, stream>>>(R2, C, khp);
        k_fft_y<<<g_t, b256, 0, stream>>>(C, khp, -1.0f);
        k_fft_x_acc<<<g_t, b256, 0, stream>>>(C, Acc, khp, 2, 2);
        k_fft_y<<<g_t, b256, 0, stream>>>(Acc, khp, 1.0f);            // inverse y
        k_irfft_z<<<g_z, b256, 0, stream>>>(Acc, out, khp, R0, sc, 1);  // + dot(W,phi)
    } else {
        const float* Np[3] = {Nxp, Nyp, Nzp};
        for (int d = 0; d < 3; d++) {
            if (mode == 1) k_rastgp<<<g_cell, b256, 0, stream>>>(Vs, Np[d], offp, R0);
            else           k_rastg<<<g_cell, b256, 0, stream>>>(idx, offp, V, N, R0, d);
            k_rfft_z<<<g_z, b256, 0, stream>>>(R0, C, khp);
            k_fft_y<<<g_t, b256, 0, stream>>>(C, khp, -1.0f);
            k_fft_x_acc<<<g_t, b256, 0, stream>>>(C, Acc, khp, d, d);
        }
        k_fft_y<<<g_t, b256, 0, stream>>>(Acc, khp, 1.0f);
        k_irfft_z<<<g_z, b256, 0, stream>>>(Acc, out, khp, (const float*)0, sc, 0);
        k_interp_sum<<<g_pts, b256, 0, stream>>>(out, V, sc);
    }

    k_scalars<<<1, 1, 0, stream>>>(sc, out, sc + 1);
    k_scale<<<16777216 / 4 / 256, 256, 0, stream>>>(out, sc + 1);
}

// Round 6
// 961.557 us; speedup vs baseline: 1.1710x; 1.0560x over previous
//
#include <hip/hip_runtime.h>
#include <math.h>

#define NPTS 500000
#define KH 129
#define NKEY 16384   // 32x32x16 cells of 8x8x16 voxels

__device__ __forceinline__ int rev4(int n) {
    return ((n & 3) << 6) | ((n & 12) << 2) | ((n & 48) >> 2) | ((n & 192) >> 6);
}

__device__ __forceinline__ void cmul(float ar, float ai, float br, float bi,
                                     float& cr, float& ci) {
    cr = ar * br - ai * bi;
    ci = ar * bi + ai * br;
}

// 16 independent 256-pt radix-4 DIT FFTs in LDS (SoA, line stride 257 floats).
__device__ void fft256x16(float* RE, float* IM, int tid, float sign) {
    const int line = tid >> 4, lane = tid & 15;
    float* re = RE + line * 257;
    float* im = IM + line * 257;
    __syncthreads();
    #pragma unroll
    for (int st = 0; st < 4; st++) {
        const int q = 1 << (2 * st);           // 1,4,16,64
        const float base = sign * 6.283185307179586f / (float)(q << 2);
        #pragma unroll
        for (int jj = 0; jj < 4; jj++) {
            const int j = lane + (jj << 4);    // 0..63
            const int pos = j & (q - 1);
            const int i0 = ((j >> (2 * st)) << (2 * st + 2)) + pos;
            const int i1 = i0 + q, i2 = i1 + q, i3 = i2 + q;
            float w1i, w1r;
            __sincosf(base * (float)pos, &w1i, &w1r);
            float w2r, w2i; cmul(w1r, w1i, w1r, w1i, w2r, w2i);
            float w3r, w3i; cmul(w2r, w2i, w1r, w1i, w3r, w3i);
            float ar = re[i0], ai = im[i0];
            float b0r = re[i1], b0i = im[i1];
            float c0r = re[i2], c0i = im[i2];
            float d0r = re[i3], d0i = im[i3];
            float br, bi; cmul(b0r, b0i, w1r, w1i, br, bi);
            float cr, ci; cmul(c0r, c0i, w2r, w2i, cr, ci);
            float dr, di; cmul(d0r, d0i, w3r, w3i, dr, di);
            float er = ar + cr, ei = ai + ci;
            float fr = ar - cr, fi = ai - ci;
            float gr = br + dr, gi = bi + di;
            float hr = br - dr, hi_ = bi - di;
            float sir = -sign * hi_, sii = sign * hr;   // sign*i*(b-d)
            re[i0] = er + gr;  im[i0] = ei + gi;
            re[i1] = fr + sir; im[i1] = fi + sii;
            re[i2] = er - gr;  im[i2] = ei - gi;
            re[i3] = fr - sir; im[i3] = fi - sii;
        }
        __syncthreads();
    }
}

__device__ __forceinline__ int cell_key(float x, float y, float z) {
    int ix = (int)(x * 256.0f), iy = (int)(y * 256.0f), iz = (int)(z * 256.0f);
    return ((ix >> 3) << 9) | ((iy >> 3) << 4) | (iz >> 4);
}

// ---- sort pass 1: histogram of cell keys ----
__global__ void k_hist(const float* __restrict__ V, int* __restrict__ cnt) {
    int i = blockIdx.x * blockDim.x + threadIdx.x;
    if (i >= NPTS) return;
    atomicAdd(&cnt[cell_key(V[3 * i], V[3 * i + 1], V[3 * i + 2])], 1);
}

// ---- sort pass 2: exclusive scan of 16384 counts (single block) ----
__global__ void k_scan(const int* __restrict__ cnt, int* __restrict__ off,
                       int* __restrict__ cnt2) {
    __shared__ int s[256];
    int t = threadIdx.x;
    int sum = 0;
    for (int j = 0; j < 64; j++) sum += cnt[t * 64 + j];
    s[t] = sum;
    __syncthreads();
    if (t == 0) { int run = 0; for (int j = 0; j < 256; j++) { int c = s[j]; s[j] = run; run += c; } }
    __syncthreads();
    int run = s[t];
    for (int j = 0; j < 64; j++) {
        int c = cnt[t * 64 + j];
        off[t * 64 + j] = run;
        cnt2[t * 64 + j] = run;
        run += c;
    }
    if (t == 255) off[NKEY] = run;   // == NPTS
}

// ---- sort pass 3 (packed): scatter coords+normals into cell order ----
__global__ void k_scatter_pk(const float* __restrict__ V, const float* __restrict__ N,
                             int* __restrict__ cnt2, float* __restrict__ Vs,
                             float* __restrict__ Nx, float* __restrict__ Ny,
                             float* __restrict__ Nz) {
    int i = blockIdx.x * blockDim.x + threadIdx.x;
    if (i >= NPTS) return;
    float x = V[3 * i], y = V[3 * i + 1], z = V[3 * i + 2];
    int s = atomicAdd(&cnt2[cell_key(x, y, z)], 1);
    Vs[3 * s] = x; Vs[3 * s + 1] = y; Vs[3 * s + 2] = z;
    Nx[s] = N[3 * i]; Ny[s] = N[3 * i + 1]; Nz[s] = N[3 * i + 2];
}

// ---- legacy sort pass 3: scatter indices (fallback path) ----
__global__ void k_scatter(const float* __restrict__ V, int* __restrict__ cnt2,
                          int* __restrict__ idx) {
    int i = blockIdx.x * blockDim.x + threadIdx.x;
    if (i >= NPTS) return;
    int s = atomicAdd(&cnt2[cell_key(V[3 * i], V[3 * i + 1], V[3 * i + 2])], 1);
    idx[s] = i;
}

// ---- dual-channel atomic-free rasterize. Block = 8x8x16 voxel tile ----
// Channel A = Na, channel B = Nb (or all-ones if bOnes). grid (16,32,32): cz,cy,cx
__global__ void k_rastg2(const float* __restrict__ Vs, const float* __restrict__ Na,
                         const float* __restrict__ Nb, const int* __restrict__ off,
                         float* __restrict__ G0, float* __restrict__ G1, int bOnes) {
    __shared__ float t0[1024], t1[1024];
    int t = threadIdx.x;
    #pragma unroll
    for (int q = 0; q < 4; q++) { t0[t + q * 256] = 0.0f; t1[t + q * 256] = 0.0f; }
    __syncthreads();
    int CZ = blockIdx.x, CY = blockIdx.y, CX = blockIdx.z;
    int X0 = CX << 3, Y0 = CY << 3, Z0 = CZ << 4;
    #pragma unroll
    for (int cc = 0; cc < 8; cc++) {
        int cx = (CX - ((cc >> 2) & 1)) & 31;
        int cy = (CY - ((cc >> 1) & 1)) & 31;
        int cz = (CZ - (cc & 1)) & 15;
        int key = (cx << 9) | (cy << 4) | cz;
        int s = off[key], e = off[key + 1];
        for (int p = s + t; p < e; p += 256) {
            float xs = Vs[3 * p] * 256.0f, ys = Vs[3 * p + 1] * 256.0f, zs = Vs[3 * p + 2] * 256.0f;
            float va = Na[p];
            float vb = bOnes ? 1.0f : Nb[p];
            int ix0 = (int)xs, iy0 = (int)ys, iz0 = (int)zs;
            float fx = xs - ix0, fy = ys - iy0, fz = zs - iz0;
            #pragma unroll
            for (int c = 0; c < 8; c++) {
                int bx = (c >> 2) & 1, by = (c >> 1) & 1, bz = c & 1;
                int lx = ((bx ? ix0 + 1 : ix0) - X0) & 255;
                int ly = ((by ? iy0 + 1 : iy0) - Y0) & 255;
                int lz = ((bz ? iz0 + 1 : iz0) - Z0) & 255;
                if (lx < 8 && ly < 8 && lz < 16) {
                    float w = (bx ? fx : 1.0f - fx) * (by ? fy : 1.0f - fy) * (bz ? fz : 1.0f - fz);
                    int li = (((lx << 3) + ly) << 4) + lz;
                    atomicAdd(&t0[li], w * va);
                    atomicAdd(&t1[li], w * vb);
                }
            }
        }
    }
    __syncthreads();
    #pragma unroll
    for (int q = 0; q < 4; q++) {
        int l = t + q * 256;
        int lx = l >> 7, ly = (l >> 4) & 7, lz = l & 15;
        size_t a = (size_t)(((X0 + lx) << 16) | ((Y0 + ly) << 8) | (Z0 + lz));
        G0[a] = t0[l]; G1[a] = t1[l];
    }
}

// ---- legacy rasterize via idx (fallback) ----
__global__ void k_rastg(const int* __restrict__ idx, const int* __restrict__ off,
                        const float* __restrict__ V, const float* __restrict__ N,
                        float* __restrict__ R, int d) {
    __shared__ float tile[1024];
    int t = threadIdx.x;
    #pragma unroll
    for (int q = 0; q < 4; q++) tile[t + q * 256] = 0.0f;
    __syncthreads();
    int CZ = blockIdx.x, CY = blockIdx.y, CX = blockIdx.z;
    int X0 = CX << 3, Y0 = CY << 3, Z0 = CZ << 4;
    #pragma unroll
    for (int cc = 0; cc < 8; cc++) {
        int cx = (CX - ((cc >> 2) & 1)) & 31;
        int cy = (CY - ((cc >> 1) & 1)) & 31;
        int cz = (CZ - (cc & 1)) & 15;
        int key = (cx << 9) | (cy << 4) | cz;
        int s = off[key], e = off[key + 1];
        for (int p = s + t; p < e; p += 256) {
            int i = idx[p];
            float xs = V[3 * i] * 256.0f, ys = V[3 * i + 1] * 256.0f, zs = V[3 * i + 2] * 256.0f;
            float val = N[3 * i + d];
            int ix0 = (int)xs, iy0 = (int)ys, iz0 = (int)zs;
            float fx = xs - ix0, fy = ys - iy0, fz = zs - iz0;
            #pragma unroll
            for (int c = 0; c < 8; c++) {
                int bx = (c >> 2) & 1, by = (c >> 1) & 1, bz = c & 1;
                int lx = ((bx ? ix0 + 1 : ix0) - X0) & 255;
                int ly = ((by ? iy0 + 1 : iy0) - Y0) & 255;
                int lz = ((bz ? iz0 + 1 : iz0) - Z0) & 255;
                if (lx < 8 && ly < 8 && lz < 16) {
                    float w = (bx ? fx : 1.0f - fx) * (by ? fy : 1.0f - fy) * (bz ? fz : 1.0f - fz);
                    atomicAdd(&tile[(((lx << 3) + ly) << 4) + lz], w * val);
                }
            }
        }
    }
    __syncthreads();
    #pragma unroll
    for (int q = 0; q < 4; q++) {
        int l = t + q * 256;
        int lx = l >> 7, ly = (l >> 4) & 7, lz = l & 15;
        R[(size_t)(((X0 + lx) << 16) | ((Y0 + ly) << 8) | (Z0 + lz))] = tile[l];
    }
}

// ---- forward rfft along z. Block: 16 (x,y)-lines. C layout [x][y][k], row khp ----
__global__ void k_rfft_z(const float* __restrict__ R, float2* __restrict__ C, int khp) {
    __shared__ float RE[16 * 257];
    __shared__ float IM[16 * 257];
    int x = blockIdx.x, y0 = blockIdx.y * 16, tid = threadIdx.x;
    #pragma unroll
    for (int l = 0; l < 16; l++) {
        float v = R[(((size_t)x << 8) + (y0 + l)) * 256 + tid];
        RE[l * 257 + rev4(tid)] = v;
        IM[l * 257 + rev4(tid)] = 0.0f;
    }
    fft256x16(RE, IM, tid, -1.0f);
    #pragma unroll
    for (int l = 0; l < 16; l++) {
        if (tid < KH) {
            C[(((size_t)x << 8) + (y0 + l)) * khp + tid] =
                make_float2(RE[l * 257 + tid], IM[l * 257 + tid]);
        }
    }
}

// ---- complex FFT along y, in place. Block: 16 k-columns at fixed x. ----
__global__ void k_fft_y(float2* __restrict__ C, int khp, float sign) {
    __shared__ float RE[16 * 257];
    __shared__ float IM[16 * 257];
    int x = blockIdx.x, k0 = blockIdx.y * 16, tid = threadIdx.x;
    int kl = tid & 15, k = k0 + kl;
    bool valid = (k < KH);
    float2* base = C + (size_t)x * 256 * khp + k;
    #pragma unroll
    for (int it = 0; it < 16; it++) {
        int y = (tid >> 4) + it * 16;
        float2 v = valid ? base[(size_t)y * khp] : make_float2(0.0f, 0.0f);
        RE[kl * 257 + rev4(y)] = v.x;
        IM[kl * 257 + rev4(y)] = v.y;
    }
    fft256x16(RE, IM, tid, sign);
    #pragma unroll
    for (int it = 0; it < 16; it++) {
        int y = (tid >> 4) + it * 16;
        if (valid) base[(size_t)y * khp] = make_float2(RE[kl * 257 + y], IM[kl * 257 + y]);
    }
}

// ---- forward FFT along x + spectral MAC into Acc; mode2 fuses inverse-x ----
__global__ void k_fft_x_acc(const float2* __restrict__ C, float2* __restrict__ Acc,
                            int khp, int mode, int d) {
    __shared__ float RE[16 * 257];
    __shared__ float IM[16 * 257];
    int y = blockIdx.x, k0 = blockIdx.y * 16, tid = threadIdx.x;
    int kl = tid & 15, k = k0 + kl;
    bool valid = (k < KH);
    size_t plane = (size_t)256 * khp;
    const float2* base = C + (size_t)y * khp + k;
    #pragma unroll
    for (int it = 0; it < 16; it++) {
        int n = (tid >> 4) + it * 16;
        float2 v = valid ? base[(size_t)n * plane] : make_float2(0.0f, 0.0f);
        RE[kl * 257 + rev4(n)] = v.x;
        IM[kl * 257 + rev4(n)] = v.y;
    }
    fft256x16(RE, IM, tid, -1.0f);
    float2* abase = Acc + (size_t)y * khp + k;
    float fy = (y < 128) ? (float)y : (float)(y - 256);
    float fz = (float)k;
    float vr[16], vi[16];
    #pragma unroll
    for (int it = 0; it < 16; it++) {
        int n = (tid >> 4) + it * 16;
        float fx = (n < 128) ? (float)n : (float)(n - 256);
        float f2 = fx * fx + fy * fy + fz * fz;
        float G = __expf(-0.0030517578125f * f2);          // exp(-0.5*(2*SIG*|f|/256)^2)
        float fd = (d == 0) ? fx : ((d == 1) ? fy : fz);
        float s = G * (6.283185307179586f * fd) / (1e-6f - 39.47841760435743f * f2);
        float xr = RE[kl * 257 + n], xi = IM[kl * 257 + n];
        float cr = s * xi, ci = -s * xr;                   // (-i*s)*v
        if (mode >= 1) {
            float2 old = valid ? abase[(size_t)n * plane] : make_float2(0.0f, 0.0f);
            cr += old.x; ci += old.y;
        }
        if (mode == 2) { vr[it] = cr; vi[it] = ci; }
        else if (valid) abase[(size_t)n * plane] = make_float2(cr, ci);
    }
    if (mode == 2) {
        __syncthreads();
        #pragma unroll
        for (int it = 0; it < 16; it++) {
            int n = (tid >> 4) + it * 16;
            RE[kl * 257 + rev4(n)] = vr[it];
            IM[kl * 257 + rev4(n)] = vi[it];
        }
        fft256x16(RE, IM, tid, 1.0f);
        #pragma unroll
        for (int it = 0; it < 16; it++) {
            int n = (tid >> 4) + it * 16;
            if (valid) abase[(size_t)n * plane] =
                make_float2(RE[kl * 257 + n], IM[kl * 257 + n]);
        }
    }
}

// ---- inverse rfft along z; optional fused dot(W, phi). NOTE: W may alias out
// (each address read by exactly one thread before that same thread stores it),
// so W/out are intentionally NOT __restrict__. ----
__global__ void k_irfft_z(const float2* __restrict__ A, float* out, int khp,
                          const float* W, float* __restrict__ S, int fuse) {
    __shared__ float RE[16 * 257];
    __shared__ float IM[16 * 257];
    __shared__ float red[4];
    int x = blockIdx.x, y0 = blockIdx.y * 16, tid = threadIdx.x;
    #pragma unroll
    for (int l = 0; l < 16; l++) {
        const float2* src = A + (((size_t)x << 8) + (y0 + l)) * khp;
        int n = tid;
        int k = (n <= 128) ? n : 256 - n;
        float2 v = src[k];
        RE[l * 257 + rev4(n)] = v.x;
        IM[l * 257 + rev4(n)] = (n <= 128) ? v.y : -v.y;
    }
    fft256x16(RE, IM, tid, 1.0f);
    const float sc = 1.0f / 16777216.0f;
    float acc = 0.0f;
    #pragma unroll
    for (int l = 0; l < 16; l++) {
        size_t a = (((size_t)x << 8) + (y0 + l)) * 256 + tid;
        float v = RE[l * 257 + tid] * sc;
        if (fuse) {
            float wv = W[a];        // load W first — may alias out[a]
            acc += v * wv;
        }
        out[a] = v;
    }
    if (fuse) {
        #pragma unroll
        for (int o = 32; o > 0; o >>= 1) acc += __shfl_down(acc, o, 64);
        if ((tid & 63) == 0) red[tid >> 6] = acc;
        __syncthreads();
        if (tid == 0) atomicAdd(S, red[0] + red[1] + red[2] + red[3]);
    }
}

// ---- legacy per-point interp (fallback) ----
__global__ void k_interp_sum(const float* __restrict__ phi, const float* __restrict__ V,
                             float* __restrict__ S) {
    int i = blockIdx.x * blockDim.x + threadIdx.x;
    float acc = 0.0f;
    if (i < NPTS) {
        float xs = V[3 * i + 0] * 256.0f;
        float ys = V[3 * i + 1] * 256.0f;
        float zs = V[3 * i + 2] * 256.0f;
        int ix0 = (int)floorf(xs), iy0 = (int)floorf(ys), iz0 = (int)floorf(zs);
        float fx = xs - (float)ix0, fy = ys - (float)iy0, fz = zs - (float)iz0;
        int ix1 = (ix0 + 1) & 255, iy1 = (iy0 + 1) & 255, iz1 = (iz0 + 1) & 255;
        #pragma unroll
        for (int c = 0; c < 8; c++) {
            int bx = (c >> 2) & 1, by = (c >> 1) & 1, bz = c & 1;
            int ix = bx ? ix1 : ix0, iy = by ? iy1 : iy0, iz = bz ? iz1 : iz0;
            float w = (bx ? fx : 1.0f - fx) * (by ? fy : 1.0f - fy) * (bz ? fz : 1.0f - fz);
            acc += w * phi[(((size_t)ix << 8) + (size_t)iy) * 256 + (size_t)iz];
        }
    }
    #pragma unroll
    for (int o = 32; o > 0; o >>= 1) acc += __shfl_down(acc, o, 64);
    if ((threadIdx.x & 63) == 0) atomicAdd(S, acc);
}

__global__ void k_scalars(const float* __restrict__ S, const float* __restrict__ phi,
                          float* __restrict__ sc_out) {
    float mean = S[0] * (1.0f / (float)NPTS);
    sc_out[0] = mean;
    sc_out[1] = 0.5f / fabsf(phi[0] - mean);
}

__global__ void k_scale(float* __restrict__ phi, const float* __restrict__ sc) {
    size_t i = (size_t)blockIdx.x * blockDim.x + threadIdx.x;
    float mean = sc[0], inv = sc[1];
    float4* p = (float4*)phi;
    float4 v = p[i];
    v.x = -(v.x - mean) * inv;
    v.y = -(v.y - mean) * inv;
    v.z = -(v.z - mean) * inv;
    v.w = -(v.w - mean) * inv;
    p[i] = v;
}

extern "C" void kernel_launch(void* const* d_in, const int* in_sizes, int n_in,
                              void* d_out, int out_size, void* d_ws, size_t ws_size,
                              hipStream_t stream) {
    const float* V = (const float*)d_in[0];
    const float* N = (const float*)d_in[1];
    float* out = (float*)d_out;

    const size_t RB   = 256ull * 256 * 256 * 4;               // 64 MiB
    const size_t C129 = 256ull * 256 * 129 * 8;
    const size_t C144 = 256ull * 256 * 144 * 8;
    const size_t SB_CNT = ((NKEY * 4 + 255) / 256) * 256;
    const size_t SB_OFF = (((NKEY + 1) * 4 + 255) / 256) * 256;
    const size_t SB_IDX = ((NPTS * 4 + 255) / 256) * 256;
    const size_t PK_VS  = ((NPTS * 3 * 4 + 255) / 256) * 256;
    const size_t PK_N   = ((NPTS * 4 + 255) / 256) * 256;
    const size_t SORT_CORE = SB_CNT * 2 + SB_OFF;             // cnt + cnt2 + off
    const size_t PACK = PK_VS + 3 * PK_N;

    // mode 1 = packed 2-walk path (W in d_out, fused dot), mode 0 = legacy
    int mode, khp; size_t cb;
    if      (ws_size >= RB + 2 * C144 + 256 + SORT_CORE + PACK)   { mode = 1; khp = 144; cb = C144; }
    else if (ws_size >= RB + 2 * C129 + 256 + SORT_CORE + PACK)   { mode = 1; khp = 129; cb = C129; }
    else if (ws_size >= RB + 2 * C144 + 256 + SORT_CORE + SB_IDX) { mode = 0; khp = 144; cb = C144; }
    else if (ws_size >= RB + 2 * C129 + 256 + SORT_CORE + SB_IDX) { mode = 0; khp = 129; cb = C129; }
    else return;

    char* ws = (char*)d_ws;
    float* R0   = (float*)ws;
    float2* C   = (float2*)(ws + RB);
    float2* Acc = (float2*)(ws + RB + cb);
    float*  sc  = (float*)(ws + RB + 2 * cb);                 // [0]=S, [1]=mean, [2]=inv
    char* sb = ws + RB + 2 * cb + 256;
    int* cnt  = (int*)sb;
    int* offp = (int*)(sb + SB_CNT);
    int* cnt2 = (int*)(sb + SB_CNT + SB_OFF);
    char* pb = sb + SORT_CORE;
    float* Vs  = (float*)pb;
    float* Nxp = (float*)(pb + PK_VS);
    float* Nyp = (float*)(pb + PK_VS + PK_N);
    float* Nzp = (float*)(pb + PK_VS + 2 * PK_N);
    int* idx = (int*)pb;   // legacy path reuses pack region

    hipMemsetAsync(sc, 0, 16, stream);
    hipMemsetAsync(cnt, 0, NKEY * 4, stream);

    dim3 b256(256);
    dim3 g_z(256, 16);
    dim3 g_t(256, 9);
    dim3 g_pts((NPTS + 255) / 256);
    dim3 g_cell(16, 32, 32);   // cz, cy, cx

    k_hist<<<g_pts, b256, 0, stream>>>(V, cnt);
    k_scan<<<1, b256, 0, stream>>>(cnt, offp, cnt2);

    if (mode == 1) {
        k_scatter_pk<<<g_pts, b256, 0, stream>>>(V, N, cnt2, Vs, Nxp, Nyp, Nzp);
        // walk A: Nx -> R0, Ny -> out
        k_rastg2<<<g_cell, b256, 0, stream>>>(Vs, Nxp, Nyp, offp, R0, out, 0);
        k_rfft_z<<<g_z, b256, 0, stream>>>(R0, C, khp);
        k_fft_y<<<g_t, b256, 0, stream>>>(C, khp, -1.0f);
        k_fft_x_acc<<<g_t, b256, 0, stream>>>(C, Acc, khp, 0, 0);
        k_rfft_z<<<g_z, b256, 0, stream>>>(out, C, khp);
        k_fft_y<<<g_t, b256, 0, stream>>>(C, khp, -1.0f);
        k_fft_x_acc<<<g_t, b256, 0, stream>>>(C, Acc, khp, 1, 1);
        // walk B: Nz -> R0, W(ones) -> out
        k_rastg2<<<g_cell, b256, 0, stream>>>(Vs, Nzp, (const float*)0, offp, R0, out, 1);
        k_rfft_z<<<g_z, b256, 0, stream>>>(R0, C, khp);
        k_fft_y<<<g_t, b256, 0, stream>>>(C, khp, -1.0f);
        k_fft_x_acc<<<g_t, b256, 0, stream>>>(C, Acc, khp, 2, 2);   // fused inverse-x
        k_fft_y<<<g_t, b256, 0, stream>>>(Acc, khp, 1.0f);          // inverse y
        k_irfft_z<<<g_z, b256, 0, stream>>>(Acc, out, khp, out, sc, 1);  // phi + dot(W,phi)
    } else {
        k_scatter<<<g_pts, b256, 0, stream>>>(V, cnt2, idx);
        for (int d = 0; d < 3; d++) {
            k_rastg<<<g_cell, b256, 0, stream>>>(idx, offp, V, N, R0, d);
            k_rfft_z<<<g_z, b256, 0, stream>>>(R0, C, khp);
            k_fft_y<<<g_t, b256, 0, stream>>>(C, khp, -1.0f);
            k_fft_x_acc<<<g_t, b256, 0, stream>>>(C, Acc, khp, d, d);
        }
        k_fft_y<<<g_t, b256, 0, stream>>>(Acc, khp, 1.0f);
        k_irfft_z<<<g_z, b256, 0, stream>>>(Acc, out, khp, (const float*)0, sc, 0);
        k_interp_sum<<<g_pts, b256, 0, stream>>>(out, V, sc);
    }

    k_scalars<<<1, 1, 0, stream>>>(sc, out, sc + 1);
    k_scale<<<16777216 / 4 / 256, 256, 0, stream>>>(out, sc + 1);
}

// Round 7
// 817.381 us; speedup vs baseline: 1.3776x; 1.1764x over previous
//
#include <hip/hip_runtime.h>
#include <math.h>

#define NPTS 500000
#define KH 129
#define NKEY 16384   // 32x32x16 cells of 8x8x16 voxels
#define LSTR 260     // LDS line stride (floats): 16B-aligned, breaks pow2 conflicts

// ---------------- radix-16 x radix-16 register FFT ----------------
template<int SIGN>
__device__ __forceinline__ void dft4v(float& ar, float& ai, float& br, float& bi,
                                      float& cr, float& ci, float& dr, float& di) {
    float t0r = ar + cr, t0i = ai + ci;
    float t1r = ar - cr, t1i = ai - ci;
    float t2r = br + dr, t2i = bi + di;
    float t3r = br - dr, t3i = bi - di;
    ar = t0r + t2r; ai = t0i + t2i;
    cr = t0r - t2r; ci = t0i - t2i;
    if (SIGN < 0) { br = t1r + t3i; bi = t1i - t3r; dr = t1r - t3i; di = t1i + t3r; }
    else          { br = t1r - t3i; bi = t1i + t3r; dr = t1r + t3i; di = t1i - t3r; }
}

template<int SIGN>
__device__ __forceinline__ void twmul(float& r, float& i, float c, float s) {
    float s_ = (SIGN < 0) ? -s : s;
    float ar = r, ai = i;
    r = ar * c - ai * s_;
    i = ar * s_ + ai * c;
}

// 16-pt DFT, natural input v[0..15]; output X[k] lands in slot perm4(k)=((k&3)<<2)|(k>>2)
template<int SIGN>
__device__ __forceinline__ void dft16(float* vr, float* vi) {
    #pragma unroll
    for (int n2 = 0; n2 < 4; n2++)
        dft4v<SIGN>(vr[n2], vi[n2], vr[n2+4], vi[n2+4], vr[n2+8], vi[n2+8], vr[n2+12], vi[n2+12]);
    const float C1 = 0.923879532511287f, S1 = 0.382683432365090f;
    const float C2 = 0.707106781186548f, S2 = 0.707106781186548f;
    const float C3 = 0.382683432365090f, S3 = 0.923879532511287f;
    twmul<SIGN>(vr[5],  vi[5],  C1, S1);    // n2=1,k1=1  m=1
    twmul<SIGN>(vr[6],  vi[6],  C2, S2);    // n2=2,k1=1  m=2
    twmul<SIGN>(vr[7],  vi[7],  C3, S3);    // n2=3,k1=1  m=3
    twmul<SIGN>(vr[9],  vi[9],  C2, S2);    // n2=1,k1=2  m=2
    twmul<SIGN>(vr[10], vi[10], 0.0f, 1.0f);// n2=2,k1=2  m=4
    twmul<SIGN>(vr[11], vi[11], -C2, S2);   // n2=3,k1=2  m=6
    twmul<SIGN>(vr[13], vi[13], C3, S3);    // n2=1,k1=3  m=3
    twmul<SIGN>(vr[14], vi[14], -C2, S2);   // n2=2,k1=3  m=6
    twmul<SIGN>(vr[15], vi[15], -C1, -S1);  // n2=3,k1=3  m=9
    #pragma unroll
    for (int k1 = 0; k1 < 4; k1++)
        dft4v<SIGN>(vr[4*k1], vi[4*k1], vr[4*k1+1], vi[4*k1+1],
                    vr[4*k1+2], vi[4*k1+2], vr[4*k1+3], vi[4*k1+3]);
}

// 16 independent 256-pt FFTs (SoA in LDS, line stride LSTR, natural order in/out).
// Thread t: line t>>4, lane t&15. All 16 lanes of a line are in one wave.
template<int SIGN>
__device__ void fft256x16_t(float* RE, float* IM, int tid) {
    const int line = tid >> 4, lane = tid & 15;
    float* re = RE + line * LSTR;
    float* im = IM + line * LSTR;
    __syncthreads();                       // staging visibility
    float vr[16], vi[16];
    #pragma unroll
    for (int m = 0; m < 16; m++) { vr[m] = re[16*m + lane]; vi[m] = im[16*m + lane]; }
    dft16<SIGN>(vr, vi);
    // inter-stage twiddle W256^{lane*k1}: 1 sincos + incremental cmuls
    float stepi, stepr;
    __sincosf((float)SIGN * 0.0245436926066f * (float)lane, &stepi, &stepr);
    float wr = stepr, wi = stepi;          // step^1
    #pragma unroll
    for (int k1 = 1; k1 < 16; k1++) {
        int s = ((k1 & 3) << 2) | (k1 >> 2);
        float ar = vr[s], ai = vi[s];
        vr[s] = ar * wr - ai * wi; vi[s] = ar * wi + ai * wr;
        float nr = wr * stepr - wi * stepi, ni = wr * stepi + wi * stepr;
        wr = nr; wi = ni;
    }
    // transpose: A[k1] -> pos k1*16+lane (strided write)
    #pragma unroll
    for (int k1 = 0; k1 < 16; k1++) {
        int s = ((k1 & 3) << 2) | (k1 >> 2);
        re[k1*16 + lane] = vr[s]; im[k1*16 + lane] = vi[s];
    }
    __syncthreads();
    // contiguous read (b128-able): lane j holds A[j, n2] for n2=0..15
    #pragma unroll
    for (int n2 = 0; n2 < 16; n2++) { vr[n2] = re[lane*16 + n2]; vi[n2] = im[lane*16 + n2]; }
    dft16<SIGN>(vr, vi);
    // X[lane + 16*k2] at slot perm4(k2) -> natural position
    #pragma unroll
    for (int k2 = 0; k2 < 16; k2++) {
        int s = ((k2 & 3) << 2) | (k2 >> 2);
        re[16*k2 + lane] = vr[s]; im[16*k2 + lane] = vi[s];
    }
    __syncthreads();
}

__device__ __forceinline__ void fft256x16(float* RE, float* IM, int tid, float sign) {
    if (sign < 0.0f) fft256x16_t<-1>(RE, IM, tid);
    else             fft256x16_t<1>(RE, IM, tid);
}

__device__ __forceinline__ int cell_key(float x, float y, float z) {
    int ix = (int)(x * 256.0f), iy = (int)(y * 256.0f), iz = (int)(z * 256.0f);
    return ((ix >> 3) << 9) | ((iy >> 3) << 4) | (iz >> 4);
}

// ---- sort pass 1: histogram of cell keys ----
__global__ void k_hist(const float* __restrict__ V, int* __restrict__ cnt) {
    int i = blockIdx.x * blockDim.x + threadIdx.x;
    if (i >= NPTS) return;
    atomicAdd(&cnt[cell_key(V[3 * i], V[3 * i + 1], V[3 * i + 2])], 1);
}

// ---- sort pass 2: exclusive scan of 16384 counts (single block) ----
__global__ void k_scan(const int* __restrict__ cnt, int* __restrict__ off,
                       int* __restrict__ cnt2) {
    __shared__ int s[256];
    int t = threadIdx.x;
    int sum = 0;
    for (int j = 0; j < 64; j++) sum += cnt[t * 64 + j];
    s[t] = sum;
    __syncthreads();
    if (t == 0) { int run = 0; for (int j = 0; j < 256; j++) { int c = s[j]; s[j] = run; run += c; } }
    __syncthreads();
    int run = s[t];
    for (int j = 0; j < 64; j++) {
        int c = cnt[t * 64 + j];
        off[t * 64 + j] = run;
        cnt2[t * 64 + j] = run;
        run += c;
    }
    if (t == 255) off[NKEY] = run;   // == NPTS
}

// ---- sort pass 3 (packed): scatter coords+normals into cell order ----
__global__ void k_scatter_pk(const float* __restrict__ V, const float* __restrict__ N,
                             int* __restrict__ cnt2, float* __restrict__ Vs,
                             float* __restrict__ Nx, float* __restrict__ Ny,
                             float* __restrict__ Nz) {
    int i = blockIdx.x * blockDim.x + threadIdx.x;
    if (i >= NPTS) return;
    float x = V[3 * i], y = V[3 * i + 1], z = V[3 * i + 2];
    int s = atomicAdd(&cnt2[cell_key(x, y, z)], 1);
    Vs[3 * s] = x; Vs[3 * s + 1] = y; Vs[3 * s + 2] = z;
    Nx[s] = N[3 * i]; Ny[s] = N[3 * i + 1]; Nz[s] = N[3 * i + 2];
}

// ---- legacy sort pass 3: scatter indices (fallback path) ----
__global__ void k_scatter(const float* __restrict__ V, int* __restrict__ cnt2,
                          int* __restrict__ idx) {
    int i = blockIdx.x * blockDim.x + threadIdx.x;
    if (i >= NPTS) return;
    int s = atomicAdd(&cnt2[cell_key(V[3 * i], V[3 * i + 1], V[3 * i + 2])], 1);
    idx[s] = i;
}

// ---- dual-channel atomic-free rasterize. Block = 8x8x16 voxel tile ----
__global__ void k_rastg2(const float* __restrict__ Vs, const float* __restrict__ Na,
                         const float* __restrict__ Nb, const int* __restrict__ off,
                         float* __restrict__ G0, float* __restrict__ G1, int bOnes) {
    __shared__ float t0[1024], t1[1024];
    int t = threadIdx.x;
    #pragma unroll
    for (int q = 0; q < 4; q++) { t0[t + q * 256] = 0.0f; t1[t + q * 256] = 0.0f; }
    __syncthreads();
    int CZ = blockIdx.x, CY = blockIdx.y, CX = blockIdx.z;
    int X0 = CX << 3, Y0 = CY << 3, Z0 = CZ << 4;
    #pragma unroll
    for (int cc = 0; cc < 8; cc++) {
        int cx = (CX - ((cc >> 2) & 1)) & 31;
        int cy = (CY - ((cc >> 1) & 1)) & 31;
        int cz = (CZ - (cc & 1)) & 15;
        int key = (cx << 9) | (cy << 4) | cz;
        int s = off[key], e = off[key + 1];
        for (int p = s + t; p < e; p += 256) {
            float xs = Vs[3 * p] * 256.0f, ys = Vs[3 * p + 1] * 256.0f, zs = Vs[3 * p + 2] * 256.0f;
            float va = Na[p];
            float vb = bOnes ? 1.0f : Nb[p];
            int ix0 = (int)xs, iy0 = (int)ys, iz0 = (int)zs;
            float fx = xs - ix0, fy = ys - iy0, fz = zs - iz0;
            #pragma unroll
            for (int c = 0; c < 8; c++) {
                int bx = (c >> 2) & 1, by = (c >> 1) & 1, bz = c & 1;
                int lx = ((bx ? ix0 + 1 : ix0) - X0) & 255;
                int ly = ((by ? iy0 + 1 : iy0) - Y0) & 255;
                int lz = ((bz ? iz0 + 1 : iz0) - Z0) & 255;
                if (lx < 8 && ly < 8 && lz < 16) {
                    float w = (bx ? fx : 1.0f - fx) * (by ? fy : 1.0f - fy) * (bz ? fz : 1.0f - fz);
                    int li = (((lx << 3) + ly) << 4) + lz;
                    atomicAdd(&t0[li], w * va);
                    atomicAdd(&t1[li], w * vb);
                }
            }
        }
    }
    __syncthreads();
    #pragma unroll
    for (int q = 0; q < 4; q++) {
        int l = t + q * 256;
        int lx = l >> 7, ly = (l >> 4) & 7, lz = l & 15;
        size_t a = (size_t)(((X0 + lx) << 16) | ((Y0 + ly) << 8) | (Z0 + lz));
        G0[a] = t0[l]; G1[a] = t1[l];
    }
}

// ---- legacy rasterize via idx (fallback) ----
__global__ void k_rastg(const int* __restrict__ idx, const int* __restrict__ off,
                        const float* __restrict__ V, const float* __restrict__ N,
                        float* __restrict__ R, int d) {
    __shared__ float tile[1024];
    int t = threadIdx.x;
    #pragma unroll
    for (int q = 0; q < 4; q++) tile[t + q * 256] = 0.0f;
    __syncthreads();
    int CZ = blockIdx.x, CY = blockIdx.y, CX = blockIdx.z;
    int X0 = CX << 3, Y0 = CY << 3, Z0 = CZ << 4;
    #pragma unroll
    for (int cc = 0; cc < 8; cc++) {
        int cx = (CX - ((cc >> 2) & 1)) & 31;
        int cy = (CY - ((cc >> 1) & 1)) & 31;
        int cz = (CZ - (cc & 1)) & 15;
        int key = (cx << 9) | (cy << 4) | cz;
        int s = off[key], e = off[key + 1];
        for (int p = s + t; p < e; p += 256) {
            int i = idx[p];
            float xs = V[3 * i] * 256.0f, ys = V[3 * i + 1] * 256.0f, zs = V[3 * i + 2] * 256.0f;
            float val = N[3 * i + d];
            int ix0 = (int)xs, iy0 = (int)ys, iz0 = (int)zs;
            float fx = xs - ix0, fy = ys - iy0, fz = zs - iz0;
            #pragma unroll
            for (int c = 0; c < 8; c++) {
                int bx = (c >> 2) & 1, by = (c >> 1) & 1, bz = c & 1;
                int lx = ((bx ? ix0 + 1 : ix0) - X0) & 255;
                int ly = ((by ? iy0 + 1 : iy0) - Y0) & 255;
                int lz = ((bz ? iz0 + 1 : iz0) - Z0) & 255;
                if (lx < 8 && ly < 8 && lz < 16) {
                    float w = (bx ? fx : 1.0f - fx) * (by ? fy : 1.0f - fy) * (bz ? fz : 1.0f - fz);
                    atomicAdd(&tile[(((lx << 3) + ly) << 4) + lz], w * val);
                }
            }
        }
    }
    __syncthreads();
    #pragma unroll
    for (int q = 0; q < 4; q++) {
        int l = t + q * 256;
        int lx = l >> 7, ly = (l >> 4) & 7, lz = l & 15;
        R[(size_t)(((X0 + lx) << 16) | ((Y0 + ly) << 8) | (Z0 + lz))] = tile[l];
    }
}

// ---- forward rfft along z. Block: 16 (x,y)-lines. C layout [x][y][k], row khp ----
__global__ void k_rfft_z(const float* __restrict__ R, float2* __restrict__ C, int khp) {
    __shared__ __align__(16) float RE[16 * LSTR];
    __shared__ __align__(16) float IM[16 * LSTR];
    int x = blockIdx.x, y0 = blockIdx.y * 16, tid = threadIdx.x;
    #pragma unroll
    for (int l = 0; l < 16; l++) {
        float v = R[(((size_t)x << 8) + (y0 + l)) * 256 + tid];
        RE[l * LSTR + tid] = v;
        IM[l * LSTR + tid] = 0.0f;
    }
    fft256x16(RE, IM, tid, -1.0f);
    #pragma unroll
    for (int l = 0; l < 16; l++) {
        if (tid < KH) {
            C[(((size_t)x << 8) + (y0 + l)) * khp + tid] =
                make_float2(RE[l * LSTR + tid], IM[l * LSTR + tid]);
        }
    }
}

// ---- complex FFT along y, in place. Block: 16 k-columns at fixed x. ----
__global__ void k_fft_y(float2* __restrict__ C, int khp, float sign) {
    __shared__ __align__(16) float RE[16 * LSTR];
    __shared__ __align__(16) float IM[16 * LSTR];
    int x = blockIdx.x, k0 = blockIdx.y * 16, tid = threadIdx.x;
    int kl = tid & 15, k = k0 + kl;
    bool valid = (k < KH);
    float2* base = C + (size_t)x * 256 * khp + k;
    #pragma unroll
    for (int it = 0; it < 16; it++) {
        int y = (tid >> 4) + it * 16;
        float2 v = valid ? base[(size_t)y * khp] : make_float2(0.0f, 0.0f);
        RE[kl * LSTR + y] = v.x;
        IM[kl * LSTR + y] = v.y;
    }
    fft256x16(RE, IM, tid, sign);
    #pragma unroll
    for (int it = 0; it < 16; it++) {
        int y = (tid >> 4) + it * 16;
        if (valid) base[(size_t)y * khp] = make_float2(RE[kl * LSTR + y], IM[kl * LSTR + y]);
    }
}

// ---- forward FFT along x + spectral MAC into Acc; mode2 fuses inverse-x ----
__global__ void k_fft_x_acc(const float2* __restrict__ C, float2* __restrict__ Acc,
                            int khp, int mode, int d) {
    __shared__ __align__(16) float RE[16 * LSTR];
    __shared__ __align__(16) float IM[16 * LSTR];
    int y = blockIdx.x, k0 = blockIdx.y * 16, tid = threadIdx.x;
    int kl = tid & 15, k = k0 + kl;
    bool valid = (k < KH);
    size_t plane = (size_t)256 * khp;
    const float2* base = C + (size_t)y * khp + k;
    #pragma unroll
    for (int it = 0; it < 16; it++) {
        int n = (tid >> 4) + it * 16;
        float2 v = valid ? base[(size_t)n * plane] : make_float2(0.0f, 0.0f);
        RE[kl * LSTR + n] = v.x;
        IM[kl * LSTR + n] = v.y;
    }
    fft256x16(RE, IM, tid, -1.0f);
    float2* abase = Acc + (size_t)y * khp + k;
    float fy = (y < 128) ? (float)y : (float)(y - 256);
    float fz = (float)k;
    float vr[16], vi[16];
    #pragma unroll
    for (int it = 0; it < 16; it++) {
        int n = (tid >> 4) + it * 16;
        float fx = (n < 128) ? (float)n : (float)(n - 256);
        float f2 = fx * fx + fy * fy + fz * fz;
        float G = __expf(-0.0030517578125f * f2);          // exp(-0.5*(2*SIG*|f|/256)^2)
        float fd = (d == 0) ? fx : ((d == 1) ? fy : fz);
        float s = G * (6.283185307179586f * fd) / (1e-6f - 39.47841760435743f * f2);
        float xr = RE[kl * LSTR + n], xi = IM[kl * LSTR + n];
        float cr = s * xi, ci = -s * xr;                   // (-i*s)*v
        if (mode >= 1) {
            float2 old = valid ? abase[(size_t)n * plane] : make_float2(0.0f, 0.0f);
            cr += old.x; ci += old.y;
        }
        if (mode == 2) { vr[it] = cr; vi[it] = ci; }
        else if (valid) abase[(size_t)n * plane] = make_float2(cr, ci);
    }
    if (mode == 2) {
        __syncthreads();   // all reads of forward result done before overwrite
        #pragma unroll
        for (int it = 0; it < 16; it++) {
            int n = (tid >> 4) + it * 16;
            RE[kl * LSTR + n] = vr[it];
            IM[kl * LSTR + n] = vi[it];
        }
        fft256x16(RE, IM, tid, 1.0f);
        #pragma unroll
        for (int it = 0; it < 16; it++) {
            int n = (tid >> 4) + it * 16;
            if (valid) abase[(size_t)n * plane] =
                make_float2(RE[kl * LSTR + n], IM[kl * LSTR + n]);
        }
    }
}

// ---- inverse rfft along z; optional fused dot(W, phi). W may alias out. ----
__global__ void k_irfft_z(const float2* __restrict__ A, float* out, int khp,
                          const float* W, float* __restrict__ S, int fuse) {
    __shared__ __align__(16) float RE[16 * LSTR];
    __shared__ __align__(16) float IM[16 * LSTR];
    __shared__ float red[4];
    int x = blockIdx.x, y0 = blockIdx.y * 16, tid = threadIdx.x;
    #pragma unroll
    for (int l = 0; l < 16; l++) {
        const float2* src = A + (((size_t)x << 8) + (y0 + l)) * khp;
        int n = tid;
        int k = (n <= 128) ? n : 256 - n;
        float2 v = src[k];
        RE[l * LSTR + n] = v.x;
        IM[l * LSTR + n] = (n <= 128) ? v.y : -v.y;
    }
    fft256x16(RE, IM, tid, 1.0f);
    const float sc = 1.0f / 16777216.0f;
    float acc = 0.0f;
    #pragma unroll
    for (int l = 0; l < 16; l++) {
        size_t a = (((size_t)x << 8) + (y0 + l)) * 256 + tid;
        float v = RE[l * LSTR + tid] * sc;
        if (fuse) {
            float wv = W[a];        // load W first — may alias out[a]
            acc += v * wv;
        }
        out[a] = v;
    }
    if (fuse) {
        #pragma unroll
        for (int o = 32; o > 0; o >>= 1) acc += __shfl_down(acc, o, 64);
        if ((tid & 63) == 0) red[tid >> 6] = acc;
        __syncthreads();
        if (tid == 0) atomicAdd(S, red[0] + red[1] + red[2] + red[3]);
    }
}

// ---- legacy per-point interp (fallback) ----
__global__ void k_interp_sum(const float* __restrict__ phi, const float* __restrict__ V,
                             float* __restrict__ S) {
    int i = blockIdx.x * blockDim.x + threadIdx.x;
    float acc = 0.0f;
    if (i < NPTS) {
        float xs = V[3 * i + 0] * 256.0f;
        float ys = V[3 * i + 1] * 256.0f;
        float zs = V[3 * i + 2] * 256.0f;
        int ix0 = (int)floorf(xs), iy0 = (int)floorf(ys), iz0 = (int)floorf(zs);
        float fx = xs - (float)ix0, fy = ys - (float)iy0, fz = zs - (float)iz0;
        int ix1 = (ix0 + 1) & 255, iy1 = (iy0 + 1) & 255, iz1 = (iz0 + 1) & 255;
        #pragma unroll
        for (int c = 0; c < 8; c++) {
            int bx = (c >> 2) & 1, by = (c >> 1) & 1, bz = c & 1;
            int ix = bx ? ix1 : ix0, iy = by ? iy1 : iy0, iz = bz ? iz1 : iz0;
            float w = (bx ? fx : 1.0f - fx) * (by ? fy : 1.0f - fy) * (bz ? fz : 1.0f - fz);
            acc += w * phi[(((size_t)ix << 8) + (size_t)iy) * 256 + (size_t)iz];
        }
    }
    #pragma unroll
    for (int o = 32; o > 0; o >>= 1) acc += __shfl_down(acc, o, 64);
    if ((threadIdx.x & 63) == 0) atomicAdd(S, acc);
}

__global__ void k_scalars(const float* __restrict__ S, const float* __restrict__ phi,
                          float* __restrict__ sc_out) {
    float mean = S[0] * (1.0f / (float)NPTS);
    sc_out[0] = mean;
    sc_out[1] = 0.5f / fabsf(phi[0] - mean);
}

__global__ void k_scale(float* __restrict__ phi, const float* __restrict__ sc) {
    size_t i = (size_t)blockIdx.x * blockDim.x + threadIdx.x;
    float mean = sc[0], inv = sc[1];
    float4* p = (float4*)phi;
    float4 v = p[i];
    v.x = -(v.x - mean) * inv;
    v.y = -(v.y - mean) * inv;
    v.z = -(v.z - mean) * inv;
    v.w = -(v.w - mean) * inv;
    p[i] = v;
}

extern "C" void kernel_launch(void* const* d_in, const int* in_sizes, int n_in,
                              void* d_out, int out_size, void* d_ws, size_t ws_size,
                              hipStream_t stream) {
    const float* V = (const float*)d_in[0];
    const float* N = (const float*)d_in[1];
    float* out = (float*)d_out;

    const size_t RB   = 256ull * 256 * 256 * 4;               // 64 MiB
    const size_t C129 = 256ull * 256 * 129 * 8;
    const size_t C144 = 256ull * 256 * 144 * 8;
    const size_t SB_CNT = ((NKEY * 4 + 255) / 256) * 256;
    const size_t SB_OFF = (((NKEY + 1) * 4 + 255) / 256) * 256;
    const size_t SB_IDX = ((NPTS * 4 + 255) / 256) * 256;
    const size_t PK_VS  = ((NPTS * 3 * 4 + 255) / 256) * 256;
    const size_t PK_N   = ((NPTS * 4 + 255) / 256) * 256;
    const size_t SORT_CORE = SB_CNT * 2 + SB_OFF;             // cnt + cnt2 + off
    const size_t PACK = PK_VS + 3 * PK_N;

    // mode 1 = packed 2-walk path (W in d_out, fused dot), mode 0 = legacy
    int mode, khp; size_t cb;
    if      (ws_size >= RB + 2 * C144 + 256 + SORT_CORE + PACK)   { mode = 1; khp = 144; cb = C144; }
    else if (ws_size >= RB + 2 * C129 + 256 + SORT_CORE + PACK)   { mode = 1; khp = 129; cb = C129; }
    else if (ws_size >= RB + 2 * C144 + 256 + SORT_CORE + SB_IDX) { mode = 0; khp = 144; cb = C144; }
    else if (ws_size >= RB + 2 * C129 + 256 + SORT_CORE + SB_IDX) { mode = 0; khp = 129; cb = C129; }
    else return;

    char* ws = (char*)d_ws;
    float* R0   = (float*)ws;
    float2* C   = (float2*)(ws + RB);
    float2* Acc = (float2*)(ws + RB + cb);
    float*  sc  = (float*)(ws + RB + 2 * cb);                 // [0]=S, [1]=mean, [2]=inv
    char* sb = ws + RB + 2 * cb + 256;
    int* cnt  = (int*)sb;
    int* offp = (int*)(sb + SB_CNT);
    int* cnt2 = (int*)(sb + SB_CNT + SB_OFF);
    char* pb = sb + SORT_CORE;
    float* Vs  = (float*)pb;
    float* Nxp = (float*)(pb + PK_VS);
    float* Nyp = (float*)(pb + PK_VS + PK_N);
    float* Nzp = (float*)(pb + PK_VS + 2 * PK_N);
    int* idx = (int*)pb;   // legacy path reuses pack region

    hipMemsetAsync(sc, 0, 16, stream);
    hipMemsetAsync(cnt, 0, NKEY * 4, stream);

    dim3 b256(256);
    dim3 g_z(256, 16);
    dim3 g_t(256, 9);
    dim3 g_pts((NPTS + 255) / 256);
    dim3 g_cell(16, 32, 32);   // cz, cy, cx

    k_hist<<<g_pts, b256, 0, stream>>>(V, cnt);
    k_scan<<<1, b256, 0, stream>>>(cnt, offp, cnt2);

    if (mode == 1) {
        k_scatter_pk<<<g_pts, b256, 0, stream>>>(V, N, cnt2, Vs, Nxp, Nyp, Nzp);
        // walk A: Nx -> R0, Ny -> out
        k_rastg2<<<g_cell, b256, 0, stream>>>(Vs, Nxp, Nyp, offp, R0, out, 0);
        k_rfft_z<<<g_z, b256, 0, stream>>>(R0, C, khp);
        k_fft_y<<<g_t, b256, 0, stream>>>(C, khp, -1.0f);
        k_fft_x_acc<<<g_t, b256, 0, stream>>>(C, Acc, khp, 0, 0);
        k_rfft_z<<<g_z, b256, 0, stream>>>(out, C, khp);
        k_fft_y<<<g_t, b256, 0, stream>>>(C, khp, -1.0f);
        k_fft_x_acc<<<g_t, b256, 0, stream>>>(C, Acc, khp, 1, 1);
        // walk B: Nz -> R0, W(ones) -> out
        k_rastg2<<<g_cell, b256, 0, stream>>>(Vs, Nzp, (const float*)0, offp, R0, out, 1);
        k_rfft_z<<<g_z, b256, 0, stream>>>(R0, C, khp);
        k_fft_y<<<g_t, b256, 0, stream>>>(C, khp, -1.0f);
        k_fft_x_acc<<<g_t, b256, 0, stream>>>(C, Acc, khp, 2, 2);   // fused inverse-x
        k_fft_y<<<g_t, b256, 0, stream>>>(Acc, khp, 1.0f);          // inverse y
        k_irfft_z<<<g_z, b256, 0, stream>>>(Acc, out, khp, out, sc, 1);  // phi + dot(W,phi)
    } else {
        k_scatter<<<g_pts, b256, 0, stream>>>(V, cnt2, idx);
        for (int d = 0; d < 3; d++) {
            k_rastg<<<g_cell, b256, 0, stream>>>(idx, offp, V, N, R0, d);
            k_rfft_z<<<g_z, b256, 0, stream>>>(R0, C, khp);
            k_fft_y<<<g_t, b256, 0, stream>>>(C, khp, -1.0f);
            k_fft_x_acc<<<g_t, b256, 0, stream>>>(C, Acc, khp, d, d);
        }
        k_fft_y<<<g_t, b256, 0, stream>>>(Acc, khp, 1.0f);
        k_irfft_z<<<g_z, b256, 0, stream>>>(Acc, out, khp, (const float*)0, sc, 0);
        k_interp_sum<<<g_pts, b256, 0, stream>>>(out, V, sc);
    }

    k_scalars<<<1, 1, 0, stream>>>(sc, out, sc + 1);
    k_scale<<<16777216 / 4 / 256, 256, 0, stream>>>(out, sc + 1);
}